// Round 9
// baseline (701.640 us; speedup 1.0000x reference)
//
#include <hip/hip_runtime.h>

#define N_NODES 50000
#define E_EDGES 400000
#define DIM     512
#define NRSU    1000
#define NVEH    (N_NODES - NRSU)
#define NB_SCAN 196           // ceil(50000/256)
#define SEG_CHUNKS 8

typedef __attribute__((ext_vector_type(8))) __bf16 bf16x8;
typedef __attribute__((ext_vector_type(4))) float  f32x4;

struct __align__(8) ush4 { unsigned short x, y, z, w; };

// ---------- bf16 split helpers (RNE) ----------
__device__ __forceinline__ unsigned short f2bf_rne(float x) {
    unsigned u = __float_as_uint(x);
    unsigned r = u + 0x7fff + ((u >> 16) & 1);
    return (unsigned short)(r >> 16);
}
__device__ __forceinline__ float bf2f(unsigned short b) {
    return __uint_as_float((unsigned)b << 16);
}
__device__ __forceinline__ void split1(float v, unsigned short& h, unsigned short& l) {
    h = f2bf_rne(v);
    l = f2bf_rne(v - bf2f(h));
}

// ---------- async global->LDS (16B per lane) ----------
typedef __attribute__((address_space(1))) const unsigned char ga_u8;
typedef __attribute__((address_space(3))) unsigned char la_u8;
__device__ __forceinline__ void gload16(const void* g, void* l) {
    __builtin_amdgcn_global_load_lds((ga_u8*)g, (la_u8*)l, 16, 0, 0);
}

// ---------------- zero int array ----------------
__global__ void k_zero_int(int* __restrict__ p, int n) {
    int i = blockIdx.x * 256 + threadIdx.x;
    if (i < n) p[i] = 0;
}

// ---------------- zero pooled SP region ----------------
__global__ void k_zero_sp(float* __restrict__ SPpool) {
    int i = blockIdx.x * 256 + threadIdx.x;     // 500 blocks x 256 x float4 = 512k floats
    float4 z = make_float4(0.f, 0.f, 0.f, 0.f);
    *reinterpret_cast<float4*>(SPpool + (size_t)i * 4) = z;
}

// ---------------- in-degree count ----------------
__global__ void k_count(const int* __restrict__ dst, int* __restrict__ cnt) {
    int e = blockIdx.x * 256 + threadIdx.x;
    if (e < E_EDGES) atomicAdd(&cnt[dst[e]], 1);
}

// ---------------- block-wise exclusive scan ----------------
__global__ __launch_bounds__(256) void k_scan1(const int* __restrict__ cnt,
                                               int* __restrict__ rowptr,
                                               int* __restrict__ bsum) {
    __shared__ int sh[256];
    int tid = threadIdx.x;
    int i = blockIdx.x * 256 + tid;
    int v = (i < N_NODES) ? cnt[i] : 0;
    sh[tid] = v;
    __syncthreads();
    #pragma unroll
    for (int off = 1; off < 256; off <<= 1) {
        int t = (tid >= off) ? sh[tid - off] : 0;
        __syncthreads();
        sh[tid] += t;
        __syncthreads();
    }
    if (i < N_NODES) rowptr[i] = sh[tid] - v;
    if (tid == 255) bsum[blockIdx.x] = sh[255];
}

__global__ __launch_bounds__(256) void k_scan2(int* __restrict__ bsum) {
    __shared__ int sh[256];
    int tid = threadIdx.x;
    int v = (tid < NB_SCAN) ? bsum[tid] : 0;
    sh[tid] = v;
    __syncthreads();
    #pragma unroll
    for (int off = 1; off < 256; off <<= 1) {
        int t = (tid >= off) ? sh[tid - off] : 0;
        __syncthreads();
        sh[tid] += t;
        __syncthreads();
    }
    if (tid < NB_SCAN) bsum[tid] = sh[tid] - v;
}

// scan finalize + dinv + zero fill counters (merged)
__global__ void k_scan3(int* __restrict__ rowptr, const int* __restrict__ bsum,
                        int* __restrict__ cntfill, float* __restrict__ dinv) {
    int i = blockIdx.x * 256 + threadIdx.x;
    if (i < N_NODES) {
        rowptr[i] += bsum[blockIdx.x];
        int c = cntfill[i];
        dinv[i] = rsqrtf((float)c + 1.0f);   // self-loop
        cntfill[i] = 0;                      // becomes fill counter
    }
    if (i == 0) rowptr[N_NODES] = E_EDGES;
}

// ---------------- CSR fill (+ precomputed edge weights) ----------------
__global__ void k_fill(const int* __restrict__ ei, const int* __restrict__ rowptr,
                       int* __restrict__ fill, int* __restrict__ col,
                       const float* __restrict__ dinv, float* __restrict__ wnorm) {
    int e = blockIdx.x * 256 + threadIdx.x;
    if (e >= E_EDGES) return;
    int s = ei[e];
    int d = ei[E_EDGES + e];
    int p = atomicAdd(&fill[d], 1);
    int idx = rowptr[d] + p;
    col[idx] = s;
    wnorm[idx] = dinv[s] * dinv[d];
}

// ---------------- segment boundaries (batch monotone over vehicles) ----
__global__ void k_segbounds(const int* __restrict__ batch, int* __restrict__ seg) {
    int v = blockIdx.x * 256 + threadIdx.x;
    if (v >= NVEH) return;
    int b = batch[NRSU + v];
    if (v == 0) {
        for (int s = 0; s <= b; ++s) seg[s] = 0;
    } else {
        int bp = batch[NRSU + v - 1];
        for (int s = bp + 1; s <= b; ++s) seg[s] = v;
    }
    if (v == NVEH - 1) {
        for (int s = b + 1; s <= NRSU; ++s) seg[s] = NVEH;
    }
}

// ---------------- segment entry-list build (+ bscale) ----------------
__global__ void k_cnt2_init(const int* __restrict__ seg, int* __restrict__ cnt2,
                            float* __restrict__ bscale) {
    int i = blockIdx.x * 256 + threadIdx.x;
    if (i < NRSU) {
        int c = seg[i + 1] - seg[i];
        cnt2[i] = c;                        // self-loop entries
        bscale[i] = 1.0f;
        bscale[NRSU + i] = (c > 0) ? 1.0f : 0.0f;  // empty segment: ref gives exact 0
    }
}

__global__ void k_cnt2_edges(const int* __restrict__ ei, const int* __restrict__ batch,
                             int* __restrict__ cnt2) {
    int e = blockIdx.x * 256 + threadIdx.x;
    if (e >= E_EDGES) return;
    int d = ei[E_EDGES + e];
    if (d >= NRSU) atomicAdd(&cnt2[batch[d]], 1);
}

// single-block exclusive scan over 1000 (pad 1024); also zeroes fill2
__global__ __launch_bounds__(1024) void k_scan_seg(const int* __restrict__ cnt2,
                                                   int* __restrict__ rowptr2,
                                                   int* __restrict__ fill2) {
    __shared__ int sh[1024];
    int tid = threadIdx.x;
    int v = (tid < NRSU) ? cnt2[tid] : 0;
    sh[tid] = v;
    __syncthreads();
    #pragma unroll
    for (int off = 1; off < 1024; off <<= 1) {
        int t = (tid >= off) ? sh[tid - off] : 0;
        __syncthreads();
        sh[tid] += t;
        __syncthreads();
    }
    if (tid < NRSU) { rowptr2[tid] = sh[tid] - v; fill2[tid] = 0; }
    if (tid == 0)   rowptr2[NRSU] = sh[1023];
}

__global__ void k_fill2_self(const int* __restrict__ batch, const int* __restrict__ seg,
                             const float* __restrict__ dinv, const int* __restrict__ rowptr2,
                             int* __restrict__ fill2, int* __restrict__ col2,
                             float* __restrict__ w2arr) {
    int v = blockIdx.x * 256 + threadIdx.x;
    if (v >= NVEH) return;
    int node = NRSU + v;
    int b = batch[node];
    float cs = (float)(seg[b + 1] - seg[b]);
    float di = dinv[node];
    int p = atomicAdd(&fill2[b], 1);
    int idx = rowptr2[b] + p;
    col2[idx] = node;
    w2arr[idx] = di * di / cs;
}

__global__ void k_fill2_edges(const int* __restrict__ ei, const int* __restrict__ batch,
                              const int* __restrict__ seg, const float* __restrict__ dinv,
                              const int* __restrict__ rowptr2, int* __restrict__ fill2,
                              int* __restrict__ col2, float* __restrict__ w2arr) {
    int e = blockIdx.x * 256 + threadIdx.x;
    if (e >= E_EDGES) return;
    int s = ei[e];
    int d = ei[E_EDGES + e];
    if (d < NRSU) return;
    int b = batch[d];
    float cs = (float)(seg[b + 1] - seg[b]);
    int p = atomicAdd(&fill2[b], 1);
    int idx = rowptr2[b] + p;
    col2[idx] = s;
    w2arr[idx] = dinv[s] * dinv[d] / cs;
}

// ---------------- both W [K][N] -> W^T split bf16 hi/lo [N][K] ----------------
__global__ void k_wsplit(const float* __restrict__ W1, const float* __restrict__ W2,
                         unsigned short* __restrict__ W1h, unsigned short* __restrict__ W1l,
                         unsigned short* __restrict__ W2h, unsigned short* __restrict__ W2l) {
    const float* W = blockIdx.y ? W2 : W1;
    unsigned short* Wh = blockIdx.y ? W2h : W1h;
    unsigned short* Wl = blockIdx.y ? W2l : W1l;
    int n = blockIdx.x;
    for (int k = threadIdx.x; k < DIM; k += 256) {
        float v = W[(size_t)k * DIM + n];
        unsigned short h, l;
        split1(v, h, l);
        Wh[(size_t)n * DIM + k] = h;
        Wl[(size_t)n * DIM + k] = l;
    }
}

// ---------------- fp32 -> bf16 hi/lo split (vector pass, SP only) -------
__global__ void k_split(const float* __restrict__ in,
                        unsigned short* __restrict__ hi,
                        unsigned short* __restrict__ lo) {
    size_t i = ((size_t)blockIdx.x * 256 + threadIdx.x) * 4;
    float4 v = *reinterpret_cast<const float4*>(in + i);
    ush4 h, l;
    split1(v.x, h.x, l.x);
    split1(v.y, h.y, l.y);
    split1(v.z, h.z, l.z);
    split1(v.w, h.w, l.w);
    *reinterpret_cast<ush4*>(hi + i) = h;
    *reinterpret_cast<ush4*>(lo + i) = l;
}

// ---------------- split-bf16 MFMA GEMM with XOR-swizzled LDS ----------------
// MODE 1: M=2000 "[rsu; pooled]" rows -> out with concat layout, + b[col]*bscale[row]
// MODE 2: C[M x 512] = relu(A@B + bias), 1-D grid with bijective XCD remap
template<int MODE>
__global__ __launch_bounds__(256) void k_gemm_mfma(const unsigned short* __restrict__ Ah,
                                                   const unsigned short* __restrict__ Al,
                                                   const unsigned short* __restrict__ BhT,
                                                   const unsigned short* __restrict__ BlT,
                                                   float* __restrict__ C, int M,
                                                   const float* __restrict__ bias,
                                                   const float* __restrict__ bscale) {
    const int BM = 128, BN = 128, BK = 32;
    __shared__ unsigned short sAh[BM * BK];
    __shared__ unsigned short sAl[BM * BK];
    __shared__ unsigned short sBh[BN * BK];
    __shared__ unsigned short sBl[BN * BK];

    int tid = threadIdx.x;
    int wv = tid >> 6;
    int ln = tid & 63;

    int wgid;
    if (MODE == 2) {
        // bijective XCD-chunk remap: nwg = 1564 = 8*195 + 4
        const int q = 195, r = 4;
        int id = blockIdx.x;
        int xcd = id & 7, idx = id >> 3;
        wgid = (xcd < r ? xcd * (q + 1) : r * (q + 1) + (xcd - r) * q) + idx;
    } else {
        wgid = blockIdx.x;
    }
    int col0 = (wgid & 3) * BN;        // col fastest: 4 col-tiles share A row-panel
    int row0 = (wgid >> 2) * BM;

    int wr = wv >> 1, wc = wv & 1;     // 2x2 waves, each 64x64
    int fr = ln & 15;
    int ks16 = ln >> 4;                // k-chunk 0..3

    f32x4 zero = {0.f, 0.f, 0.f, 0.f};
    f32x4 acc[4][4];
    #pragma unroll
    for (int m = 0; m < 4; ++m)
        #pragma unroll
        for (int n = 0; n < 4; ++n) acc[m][n] = zero;

    for (int k0 = 0; k0 < DIM; k0 += BK) {
        __syncthreads();
        #pragma unroll
        for (int p = 0; p < 2; ++p) {
            int idx = p * 256 + tid;           // (row, slot): row = idx>>2, slot = idx&3
            int r = idx >> 2;
            int slot = idx & 3;
            int c = ((slot ^ (r & 3)) << 3);   // pre-swizzled global k-chunk
            int arow = row0 + r; if (arow > M - 1) arow = M - 1;
            size_t aoff = (size_t)arow * DIM + k0 + c;
            size_t boff = (size_t)(col0 + r) * DIM + k0 + c;
            int lbyte = p * 4096 + wv * 1024;  // linear wave-uniform LDS dest
            gload16(Ah + aoff, (char*)sAh + lbyte);
            gload16(Al + aoff, (char*)sAl + lbyte);
            gload16(BhT + boff, (char*)sBh + lbyte);
            gload16(BlT + boff, (char*)sBl + lbyte);
        }
        __syncthreads();

        bf16x8 ah[4], al[4], bh[4], bl[4];
        #pragma unroll
        for (int m = 0; m < 4; ++m) {
            int r = wr * 64 + m * 16 + fr;
            int e = r * BK + ((ks16 ^ (r & 3)) << 3);
            ah[m] = *reinterpret_cast<const bf16x8*>(&sAh[e]);
            al[m] = *reinterpret_cast<const bf16x8*>(&sAl[e]);
        }
        #pragma unroll
        for (int n = 0; n < 4; ++n) {
            int r = wc * 64 + n * 16 + fr;
            int e = r * BK + ((ks16 ^ (r & 3)) << 3);
            bh[n] = *reinterpret_cast<const bf16x8*>(&sBh[e]);
            bl[n] = *reinterpret_cast<const bf16x8*>(&sBl[e]);
        }
        #pragma unroll
        for (int m = 0; m < 4; ++m)
            #pragma unroll
            for (int n = 0; n < 4; ++n) {
                acc[m][n] = __builtin_amdgcn_mfma_f32_16x16x32_bf16(ah[m], bh[n], acc[m][n], 0, 0, 0);
                acc[m][n] = __builtin_amdgcn_mfma_f32_16x16x32_bf16(al[m], bh[n], acc[m][n], 0, 0, 0);
                acc[m][n] = __builtin_amdgcn_mfma_f32_16x16x32_bf16(ah[m], bl[n], acc[m][n], 0, 0, 0);
            }
    }

    int rbase = row0 + wr * 64 + (ln >> 4) * 4;
    int cbase = col0 + wc * 64 + (ln & 15);
    #pragma unroll
    for (int m = 0; m < 4; ++m)
        #pragma unroll
        for (int r4 = 0; r4 < 4; ++r4) {
            int row = rbase + m * 16 + r4;
            if (row < M) {
                if (MODE == 2) {
                    #pragma unroll
                    for (int n = 0; n < 4; ++n) {
                        int cc = cbase + n * 16;
                        C[(size_t)row * DIM + cc] = fmaxf(acc[m][n][r4] + bias[cc], 0.f);
                    }
                } else {
                    float bs = bscale[row];
                    float* dst = (row < NRSU) ? (C + (size_t)row * 1024)
                                              : (C + (size_t)(row - NRSU) * 1024 + 512);
                    #pragma unroll
                    for (int n = 0; n < 4; ++n) {
                        int cc = cbase + n * 16;
                        dst[cc] = acc[m][n][r4] + bias[cc] * bs;
                    }
                }
            }
        }
}

// ---------------- CSR gather: out = S_norm * pre; epilogue fp32 or bf16-split ----
#define FMA4(d, ww, v) d.x = fmaf(ww, v.x, d.x); d.y = fmaf(ww, v.y, d.y); \
                       d.z = fmaf(ww, v.z, d.z); d.w = fmaf(ww, v.w, d.w)

template<bool SPLIT>
__global__ __launch_bounds__(256) void k_gather(const int* __restrict__ rowptr,
                                                const int* __restrict__ col,
                                                const float* __restrict__ wnorm,
                                                const float* __restrict__ dinv,
                                                const float* __restrict__ pre,
                                                float* __restrict__ outf,
                                                unsigned short* __restrict__ oh,
                                                unsigned short* __restrict__ ol) {
    int node = blockIdx.x * 4 + (threadIdx.x >> 6);
    if (node >= N_NODES) return;
    int lane = threadIdx.x & 63;
    int c0 = lane * 4, c1 = 256 + lane * 4;

    float di = dinv[node];
    float w0 = di * di;
    const float* prow = pre + (size_t)node * DIM;
    float4 a0 = *reinterpret_cast<const float4*>(prow + c0);
    float4 a1 = *reinterpret_cast<const float4*>(prow + c1);
    float4 s0, s1;
    s0.x = w0 * a0.x; s0.y = w0 * a0.y; s0.z = w0 * a0.z; s0.w = w0 * a0.w;
    s1.x = w0 * a1.x; s1.y = w0 * a1.y; s1.z = w0 * a1.z; s1.w = w0 * a1.w;
    float4 t0 = make_float4(0.f, 0.f, 0.f, 0.f);
    float4 t1 = make_float4(0.f, 0.f, 0.f, 0.f);

    int beg = rowptr[node], end = rowptr[node + 1];
    int deg = end - beg;
    for (int j0 = 0; j0 < deg; j0 += 64) {
        int j = j0 + lane;
        int cj = 0; float wj = 0.f;
        if (j < deg) { cj = col[beg + j]; wj = wnorm[beg + j]; }
        int lim = deg - j0; if (lim > 64) lim = 64;
        for (int jj = 0; jj < lim; jj += 8) {
            int sidx[8]; float sw[8];
            #pragma unroll
            for (int q = 0; q < 8; ++q) {
                sidx[q] = __shfl(cj, jj + q);
                sw[q]   = __shfl(wj, jj + q);
            }
            float4 v0[8], v1[8];
            #pragma unroll
            for (int q = 0; q < 8; ++q) {
                const float* r = pre + (size_t)sidx[q] * DIM;
                v0[q] = *reinterpret_cast<const float4*>(r + c0);
                v1[q] = *reinterpret_cast<const float4*>(r + c1);
            }
            #pragma unroll
            for (int q = 0; q < 8; q += 2) {
                FMA4(s0, sw[q], v0[q]);     FMA4(s1, sw[q], v1[q]);
                FMA4(t0, sw[q+1], v0[q+1]); FMA4(t1, sw[q+1], v1[q+1]);
            }
        }
    }
    s0.x += t0.x; s0.y += t0.y; s0.z += t0.z; s0.w += t0.w;
    s1.x += t1.x; s1.y += t1.y; s1.z += t1.z; s1.w += t1.w;

    if (!SPLIT) {
        float* orow = outf + (size_t)node * DIM;
        *reinterpret_cast<float4*>(orow + c0) = s0;
        *reinterpret_cast<float4*>(orow + c1) = s1;
    } else {
        ush4 h0, l0, h1, l1;
        split1(s0.x, h0.x, l0.x); split1(s0.y, h0.y, l0.y);
        split1(s0.z, h0.z, l0.z); split1(s0.w, h0.w, l0.w);
        split1(s1.x, h1.x, l1.x); split1(s1.y, h1.y, l1.y);
        split1(s1.z, h1.z, l1.z); split1(s1.w, h1.w, l1.w);
        size_t base = (size_t)node * DIM;
        *reinterpret_cast<ush4*>(oh + base + c0) = h0;
        *reinterpret_cast<ush4*>(ol + base + c0) = l0;
        *reinterpret_cast<ush4*>(oh + base + c1) = h1;
        *reinterpret_cast<ush4*>(ol + base + c1) = l1;
    }
}

// ---------------- chunked segment gather: 8 blocks/segment, atomic accumulate ----
__global__ __launch_bounds__(256) void k_seg_gather(const int* __restrict__ rowptr2,
                                                    const int* __restrict__ col2,
                                                    const float* __restrict__ w2arr,
                                                    const float* __restrict__ h1,
                                                    float* __restrict__ SP) {
    int s = blockIdx.x >> 3;            // segment 0..999
    int ck = blockIdx.x & 7;            // chunk 0..7
    int tid = threadIdx.x;
    int wv = tid >> 6, lane = tid & 63;
    int c0 = lane * 4, c1 = 256 + lane * 4;
    __shared__ float red[4][DIM];

    int beg = rowptr2[s], end = rowptr2[s + 1];
    int len = end - beg;
    int clen = (len + SEG_CHUNKS - 1) >> 3;
    int cbeg = beg + ck * clen;
    int cend = cbeg + clen; if (cend > end) cend = end;
    if (cbeg > cend) cbeg = cend;

    int qlen = (cend - cbeg + 3) >> 2;
    int wbeg = cbeg + wv * qlen;
    int wend = wbeg + qlen; if (wend > cend) wend = cend;

    float4 s0 = make_float4(0.f, 0.f, 0.f, 0.f);
    float4 s1 = make_float4(0.f, 0.f, 0.f, 0.f);
    float4 t0 = make_float4(0.f, 0.f, 0.f, 0.f);
    float4 t1 = make_float4(0.f, 0.f, 0.f, 0.f);

    for (int j0 = wbeg; j0 < wend; j0 += 64) {
        int j = j0 + lane;
        int cj = 0; float wj = 0.f;
        if (j < wend) { cj = col2[j]; wj = w2arr[j]; }
        int lim = wend - j0; if (lim > 64) lim = 64;
        for (int jj = 0; jj < lim; jj += 8) {
            int sidx[8]; float sw[8];
            #pragma unroll
            for (int q = 0; q < 8; ++q) {
                sidx[q] = __shfl(cj, jj + q);
                sw[q]   = __shfl(wj, jj + q);
            }
            float4 v0[8], v1[8];
            #pragma unroll
            for (int q = 0; q < 8; ++q) {
                const float* r = h1 + (size_t)sidx[q] * DIM;
                v0[q] = *reinterpret_cast<const float4*>(r + c0);
                v1[q] = *reinterpret_cast<const float4*>(r + c1);
            }
            #pragma unroll
            for (int q = 0; q < 8; q += 2) {
                FMA4(s0, sw[q], v0[q]);     FMA4(s1, sw[q], v1[q]);
                FMA4(t0, sw[q+1], v0[q+1]); FMA4(t1, sw[q+1], v1[q+1]);
            }
        }
    }
    s0.x += t0.x; s0.y += t0.y; s0.z += t0.z; s0.w += t0.w;
    s1.x += t1.x; s1.y += t1.y; s1.z += t1.z; s1.w += t1.w;
    *reinterpret_cast<float4*>(&red[wv][c0]) = s0;
    *reinterpret_cast<float4*>(&red[wv][c1]) = s1;
    __syncthreads();

    float a = red[0][tid] + red[1][tid] + red[2][tid] + red[3][tid];
    float b = red[0][tid + 256] + red[1][tid + 256] + red[2][tid + 256] + red[3][tid + 256];
    float* orow = SP + (size_t)(NRSU + s) * DIM;
    atomicAdd(orow + tid, a);
    atomicAdd(orow + tid + 256, b);
}

extern "C" void kernel_launch(void* const* d_in, const int* in_sizes, int n_in,
                              void* d_out, int out_size, void* d_ws, size_t ws_size,
                              hipStream_t stream) {
    const float* x     = (const float*)d_in[0];
    const int*   ei    = (const int*)d_in[1];
    const int*   batch = (const int*)d_in[2];
    const float* W1    = (const float*)d_in[3];
    const float* b1    = (const float*)d_in[4];
    const float* W2    = (const float*)d_in[5];
    const float* b2    = (const float*)d_in[6];
    float* out = (float*)d_out;

    char* ws = (char*)d_ws;
    const size_t HALF = (size_t)N_NODES * DIM * 2;        // one bf16 plane (51.2 MB)
    unsigned short* Axh = (unsigned short*)(ws);
    unsigned short* Axl = (unsigned short*)(ws + HALF);
    float* h1 = (float*)(ws + 2 * HALF);
    char* p = ws + 4 * HALF;
    float* dinv    = (float*)p;                p += (size_t)N_NODES * 4;
    int*   cnt     = (int*)p;                  p += (size_t)N_NODES * 4;   // reused as fill
    int*   rowptr  = (int*)p;                  p += (size_t)(N_NODES + 4) * 4;
    int*   col     = (int*)p;                  p += (size_t)E_EDGES * 4;
    float* wnorm   = (float*)p;                p += (size_t)E_EDGES * 4;
    int*   bsum    = (int*)p;                  p += 1024;
    int*   seg     = (int*)p;                  p += (size_t)(NRSU + 8) * 4;
    int*   cnt2    = (int*)p;                  p += (size_t)(NRSU + 8) * 4;
    int*   rowptr2 = (int*)p;                  p += (size_t)(NRSU + 8) * 4;
    int*   fill2   = (int*)p;                  p += (size_t)(NRSU + 8) * 4;
    int*   col2    = (int*)p;                  p += (size_t)(E_EDGES + NVEH + 64) * 4;
    float* w2arr   = (float*)p;                p += (size_t)(E_EDGES + NVEH + 64) * 4;
    float* SP      = (float*)p;                p += (size_t)2 * NRSU * DIM * 4;
    unsigned short* SPh = (unsigned short*)p;  p += (size_t)2 * NRSU * DIM * 2;
    unsigned short* SPl = (unsigned short*)p;  p += (size_t)2 * NRSU * DIM * 2;
    float* bscale  = (float*)p;                p += (size_t)2 * NRSU * 4;
    unsigned short* W1h = (unsigned short*)p;  p += (size_t)DIM * DIM * 2;
    unsigned short* W1l = (unsigned short*)p;  p += (size_t)DIM * DIM * 2;
    unsigned short* W2h = (unsigned short*)p;  p += (size_t)DIM * DIM * 2;
    unsigned short* W2l = (unsigned short*)p;  p += (size_t)DIM * DIM * 2;

    dim3 blk(256);
    const int gN = (N_NODES + 255) / 256;
    const int gE = (E_EDGES + 255) / 256;
    const int gV = (NVEH + 255) / 256;

    // ---- CSR build + norm + seg entry lists + weight prep ----
    k_zero_int   <<<gN, blk, 0, stream>>>(cnt, N_NODES);
    k_count      <<<gE, blk, 0, stream>>>(ei + E_EDGES, cnt);
    k_scan1      <<<gN, blk, 0, stream>>>(cnt, rowptr, bsum);
    k_scan2      <<<1,  blk, 0, stream>>>(bsum);
    k_scan3      <<<gN, blk, 0, stream>>>(rowptr, bsum, cnt, dinv);
    k_fill       <<<gE, blk, 0, stream>>>(ei, rowptr, cnt, col, dinv, wnorm);
    k_segbounds  <<<gV, blk, 0, stream>>>(batch, seg);
    k_cnt2_init  <<<4,  blk, 0, stream>>>(seg, cnt2, bscale);
    k_cnt2_edges <<<gE, blk, 0, stream>>>(ei, batch, cnt2);
    k_scan_seg   <<<1, dim3(1024), 0, stream>>>(cnt2, rowptr2, fill2);
    k_fill2_self <<<gV, blk, 0, stream>>>(batch, seg, dinv, rowptr2, fill2, col2, w2arr);
    k_fill2_edges<<<gE, blk, 0, stream>>>(ei, batch, seg, dinv, rowptr2, fill2, col2, w2arr);
    k_wsplit     <<<dim3(DIM, 2), blk, 0, stream>>>(W1, W2, W1h, W1l, W2h, W2l);
    k_zero_sp    <<<(NRSU * DIM / 4) / 256, blk, 0, stream>>>(SP + (size_t)NRSU * DIM);

    // ---- layer 1 (reordered): Ax = S*x (split epilogue); h1 = relu(Ax@W1 + b1) ----
    k_gather<true><<<(N_NODES + 3) / 4, blk, 0, stream>>>(rowptr, col, wnorm, dinv, x, nullptr, Axh, Axl);
    const int NWG1 = ((N_NODES + 127) / 128) * 4;   // 1564
    k_gemm_mfma<2><<<NWG1, blk, 0, stream>>>(Axh, Axl, W1h, W1l, h1, N_NODES, b1, nullptr);

    // ---- layer 2 (pool-fused): SP = [S_rsu*h1 ; P_seg*h1]; out = SP@W2 + b2*bscale ----
    k_gather<false><<<NRSU / 4, blk, 0, stream>>>(rowptr, col, wnorm, dinv, h1, SP, nullptr, nullptr);
    k_seg_gather  <<<NRSU * SEG_CHUNKS, blk, 0, stream>>>(rowptr2, col2, w2arr, h1, SP);
    k_split       <<<(2 * NRSU * DIM / 4) / 256, blk, 0, stream>>>(SP, SPh, SPl);
    const int NWG2 = ((2 * NRSU + 127) / 128) * 4;  // 64
    k_gemm_mfma<1><<<NWG2, blk, 0, stream>>>(SPh, SPl, W2h, W2l, out, 2 * NRSU, b2, bscale);
}

// Round 10
// 521.804 us; speedup vs baseline: 1.3446x; 1.3446x over previous
//
#include <hip/hip_runtime.h>

#define N_NODES 50000
#define E_EDGES 400000
#define DIM     512
#define NRSU    1000
#define NVEH    (N_NODES - NRSU)
#define NB_SCAN 196           // ceil(50000/256)

typedef __attribute__((ext_vector_type(8))) __bf16 bf16x8;
typedef __attribute__((ext_vector_type(4))) float  f32x4;

struct __align__(8) ush4 { unsigned short x, y, z, w; };

// ---------- bf16 split helpers (RNE) ----------
__device__ __forceinline__ unsigned short f2bf_rne(float x) {
    unsigned u = __float_as_uint(x);
    unsigned r = u + 0x7fff + ((u >> 16) & 1);
    return (unsigned short)(r >> 16);
}
__device__ __forceinline__ float bf2f(unsigned short b) {
    return __uint_as_float((unsigned)b << 16);
}
__device__ __forceinline__ void split1(float v, unsigned short& h, unsigned short& l) {
    h = f2bf_rne(v);
    l = f2bf_rne(v - bf2f(h));
}

// ---------- async global->LDS (16B per lane) ----------
typedef __attribute__((address_space(1))) const unsigned char ga_u8;
typedef __attribute__((address_space(3))) unsigned char la_u8;
__device__ __forceinline__ void gload16(const void* g, void* l) {
    __builtin_amdgcn_global_load_lds((ga_u8*)g, (la_u8*)l, 16, 0, 0);
}

// ---------------- zero int array ----------------
__global__ void k_zero_int(int* __restrict__ p, int n) {
    int i = blockIdx.x * 256 + threadIdx.x;
    if (i < n) p[i] = 0;
}

// ---------------- in-degree count ----------------
__global__ void k_count(const int* __restrict__ dst, int* __restrict__ cnt) {
    int e = blockIdx.x * 256 + threadIdx.x;
    if (e < E_EDGES) atomicAdd(&cnt[dst[e]], 1);
}

// ---------------- block-wise exclusive scan ----------------
__global__ __launch_bounds__(256) void k_scan1(const int* __restrict__ cnt,
                                               int* __restrict__ rowptr,
                                               int* __restrict__ bsum) {
    __shared__ int sh[256];
    int tid = threadIdx.x;
    int i = blockIdx.x * 256 + tid;
    int v = (i < N_NODES) ? cnt[i] : 0;
    sh[tid] = v;
    __syncthreads();
    #pragma unroll
    for (int off = 1; off < 256; off <<= 1) {
        int t = (tid >= off) ? sh[tid - off] : 0;
        __syncthreads();
        sh[tid] += t;
        __syncthreads();
    }
    if (i < N_NODES) rowptr[i] = sh[tid] - v;
    if (tid == 255) bsum[blockIdx.x] = sh[255];
}

__global__ __launch_bounds__(256) void k_scan2(int* __restrict__ bsum) {
    __shared__ int sh[256];
    int tid = threadIdx.x;
    int v = (tid < NB_SCAN) ? bsum[tid] : 0;
    sh[tid] = v;
    __syncthreads();
    #pragma unroll
    for (int off = 1; off < 256; off <<= 1) {
        int t = (tid >= off) ? sh[tid - off] : 0;
        __syncthreads();
        sh[tid] += t;
        __syncthreads();
    }
    if (tid < NB_SCAN) bsum[tid] = sh[tid] - v;
}

// scan finalize + dinv + zero fill counters (merged)
__global__ void k_scan3(int* __restrict__ rowptr, const int* __restrict__ bsum,
                        int* __restrict__ cntfill, float* __restrict__ dinv) {
    int i = blockIdx.x * 256 + threadIdx.x;
    if (i < N_NODES) {
        rowptr[i] += bsum[blockIdx.x];
        int c = cntfill[i];
        dinv[i] = rsqrtf((float)c + 1.0f);   // self-loop
        cntfill[i] = 0;                      // becomes fill counter
    }
    if (i == 0) rowptr[N_NODES] = E_EDGES;
}

// ---------------- CSR fill (+ precomputed edge weights) ----------------
__global__ void k_fill(const int* __restrict__ ei, const int* __restrict__ rowptr,
                       int* __restrict__ fill, int* __restrict__ col,
                       const float* __restrict__ dinv, float* __restrict__ wnorm) {
    int e = blockIdx.x * 256 + threadIdx.x;
    if (e >= E_EDGES) return;
    int s = ei[e];
    int d = ei[E_EDGES + e];
    int p = atomicAdd(&fill[d], 1);
    int idx = rowptr[d] + p;
    col[idx] = s;
    wnorm[idx] = dinv[s] * dinv[d];
}

// ---------------- segment boundaries (batch monotone over vehicles) ----
__global__ void k_segbounds(const int* __restrict__ batch, int* __restrict__ seg) {
    int v = blockIdx.x * 256 + threadIdx.x;
    if (v >= NVEH) return;
    int b = batch[NRSU + v];
    if (v == 0) {
        for (int s = 0; s <= b; ++s) seg[s] = 0;
    } else {
        int bp = batch[NRSU + v - 1];
        for (int s = bp + 1; s <= b; ++s) seg[s] = v;
    }
    if (v == NVEH - 1) {
        for (int s = b + 1; s <= NRSU; ++s) seg[s] = NVEH;
    }
}

// ---------------- both W [K][N] -> W^T split bf16 hi/lo [N][K] ----------------
__global__ void k_wsplit(const float* __restrict__ W1, const float* __restrict__ W2,
                         unsigned short* __restrict__ W1h, unsigned short* __restrict__ W1l,
                         unsigned short* __restrict__ W2h, unsigned short* __restrict__ W2l) {
    const float* W = blockIdx.y ? W2 : W1;
    unsigned short* Wh = blockIdx.y ? W2h : W1h;
    unsigned short* Wl = blockIdx.y ? W2l : W1l;
    int n = blockIdx.x;
    for (int k = threadIdx.x; k < DIM; k += 256) {
        float v = W[(size_t)k * DIM + n];
        unsigned short h, l;
        split1(v, h, l);
        Wh[(size_t)n * DIM + k] = h;
        Wl[(size_t)n * DIM + k] = l;
    }
}

// ---------------- fp32 -> bf16 hi/lo split (vector pass, SP only) -------
__global__ void k_split(const float* __restrict__ in,
                        unsigned short* __restrict__ hi,
                        unsigned short* __restrict__ lo) {
    size_t i = ((size_t)blockIdx.x * 256 + threadIdx.x) * 4;
    float4 v = *reinterpret_cast<const float4*>(in + i);
    ush4 h, l;
    split1(v.x, h.x, l.x);
    split1(v.y, h.y, l.y);
    split1(v.z, h.z, l.z);
    split1(v.w, h.w, l.w);
    *reinterpret_cast<ush4*>(hi + i) = h;
    *reinterpret_cast<ush4*>(lo + i) = l;
}

// ---------------- split-bf16 MFMA GEMM with XOR-swizzled LDS ----------------
// MODE 1: M=2000 "[rsu; pooled]" rows -> out with concat layout, + b[col]*bscale[row]
// MODE 2: C[M x 512] = relu(A@B + bias), 1-D grid with bijective XCD remap
template<int MODE>
__global__ __launch_bounds__(256) void k_gemm_mfma(const unsigned short* __restrict__ Ah,
                                                   const unsigned short* __restrict__ Al,
                                                   const unsigned short* __restrict__ BhT,
                                                   const unsigned short* __restrict__ BlT,
                                                   float* __restrict__ C, int M,
                                                   const float* __restrict__ bias,
                                                   const float* __restrict__ bscale) {
    const int BM = 128, BN = 128, BK = 32;
    __shared__ unsigned short sAh[BM * BK];
    __shared__ unsigned short sAl[BM * BK];
    __shared__ unsigned short sBh[BN * BK];
    __shared__ unsigned short sBl[BN * BK];

    int tid = threadIdx.x;
    int wv = tid >> 6;
    int ln = tid & 63;

    int wgid;
    if (MODE == 2) {
        // bijective XCD-chunk remap: nwg = 1564 = 8*195 + 4
        const int q = 195, r = 4;
        int id = blockIdx.x;
        int xcd = id & 7, idx = id >> 3;
        wgid = (xcd < r ? xcd * (q + 1) : r * (q + 1) + (xcd - r) * q) + idx;
    } else {
        wgid = blockIdx.x;
    }
    int col0 = (wgid & 3) * BN;        // col fastest: 4 col-tiles share A row-panel
    int row0 = (wgid >> 2) * BM;

    int wr = wv >> 1, wc = wv & 1;     // 2x2 waves, each 64x64
    int fr = ln & 15;
    int ks16 = ln >> 4;                // k-chunk 0..3

    f32x4 zero = {0.f, 0.f, 0.f, 0.f};
    f32x4 acc[4][4];
    #pragma unroll
    for (int m = 0; m < 4; ++m)
        #pragma unroll
        for (int n = 0; n < 4; ++n) acc[m][n] = zero;

    for (int k0 = 0; k0 < DIM; k0 += BK) {
        __syncthreads();
        #pragma unroll
        for (int p = 0; p < 2; ++p) {
            int idx = p * 256 + tid;           // (row, slot): row = idx>>2, slot = idx&3
            int r = idx >> 2;
            int slot = idx & 3;
            int c = ((slot ^ (r & 3)) << 3);   // pre-swizzled global k-chunk
            int arow = row0 + r; if (arow > M - 1) arow = M - 1;
            size_t aoff = (size_t)arow * DIM + k0 + c;
            size_t boff = (size_t)(col0 + r) * DIM + k0 + c;
            int lbyte = p * 4096 + wv * 1024;  // linear wave-uniform LDS dest
            gload16(Ah + aoff, (char*)sAh + lbyte);
            gload16(Al + aoff, (char*)sAl + lbyte);
            gload16(BhT + boff, (char*)sBh + lbyte);
            gload16(BlT + boff, (char*)sBl + lbyte);
        }
        __syncthreads();

        bf16x8 ah[4], al[4], bh[4], bl[4];
        #pragma unroll
        for (int m = 0; m < 4; ++m) {
            int r = wr * 64 + m * 16 + fr;
            int e = r * BK + ((ks16 ^ (r & 3)) << 3);
            ah[m] = *reinterpret_cast<const bf16x8*>(&sAh[e]);
            al[m] = *reinterpret_cast<const bf16x8*>(&sAl[e]);
        }
        #pragma unroll
        for (int n = 0; n < 4; ++n) {
            int r = wc * 64 + n * 16 + fr;
            int e = r * BK + ((ks16 ^ (r & 3)) << 3);
            bh[n] = *reinterpret_cast<const bf16x8*>(&sBh[e]);
            bl[n] = *reinterpret_cast<const bf16x8*>(&sBl[e]);
        }
        #pragma unroll
        for (int m = 0; m < 4; ++m)
            #pragma unroll
            for (int n = 0; n < 4; ++n) {
                acc[m][n] = __builtin_amdgcn_mfma_f32_16x16x32_bf16(ah[m], bh[n], acc[m][n], 0, 0, 0);
                acc[m][n] = __builtin_amdgcn_mfma_f32_16x16x32_bf16(al[m], bh[n], acc[m][n], 0, 0, 0);
                acc[m][n] = __builtin_amdgcn_mfma_f32_16x16x32_bf16(ah[m], bl[n], acc[m][n], 0, 0, 0);
            }
    }

    int rbase = row0 + wr * 64 + (ln >> 4) * 4;
    int cbase = col0 + wc * 64 + (ln & 15);
    #pragma unroll
    for (int m = 0; m < 4; ++m)
        #pragma unroll
        for (int r4 = 0; r4 < 4; ++r4) {
            int row = rbase + m * 16 + r4;
            if (row < M) {
                if (MODE == 2) {
                    #pragma unroll
                    for (int n = 0; n < 4; ++n) {
                        int cc = cbase + n * 16;
                        C[(size_t)row * DIM + cc] = fmaxf(acc[m][n][r4] + bias[cc], 0.f);
                    }
                } else {
                    float bs = bscale[row];
                    float* dst = (row < NRSU) ? (C + (size_t)row * 1024)
                                              : (C + (size_t)(row - NRSU) * 1024 + 512);
                    #pragma unroll
                    for (int n = 0; n < 4; ++n) {
                        int cc = cbase + n * 16;
                        dst[cc] = acc[m][n][r4] + bias[cc] * bs;
                    }
                }
            }
        }
}

// ---------------- CSR gather: out = S_norm * pre; epilogue fp32 or bf16-split ----
#define FMA4(d, ww, v) d.x = fmaf(ww, v.x, d.x); d.y = fmaf(ww, v.y, d.y); \
                       d.z = fmaf(ww, v.z, d.z); d.w = fmaf(ww, v.w, d.w)

template<bool SPLIT>
__global__ __launch_bounds__(256) void k_gather(const int* __restrict__ rowptr,
                                                const int* __restrict__ col,
                                                const float* __restrict__ wnorm,
                                                const float* __restrict__ dinv,
                                                const float* __restrict__ pre,
                                                float* __restrict__ outf,
                                                unsigned short* __restrict__ oh,
                                                unsigned short* __restrict__ ol) {
    int node = blockIdx.x * 4 + (threadIdx.x >> 6);
    if (node >= N_NODES) return;
    int lane = threadIdx.x & 63;
    int c0 = lane * 4, c1 = 256 + lane * 4;

    float di = dinv[node];
    float w0 = di * di;
    const float* prow = pre + (size_t)node * DIM;
    float4 a0 = *reinterpret_cast<const float4*>(prow + c0);
    float4 a1 = *reinterpret_cast<const float4*>(prow + c1);
    float4 s0, s1;
    s0.x = w0 * a0.x; s0.y = w0 * a0.y; s0.z = w0 * a0.z; s0.w = w0 * a0.w;
    s1.x = w0 * a1.x; s1.y = w0 * a1.y; s1.z = w0 * a1.z; s1.w = w0 * a1.w;
    float4 t0 = make_float4(0.f, 0.f, 0.f, 0.f);
    float4 t1 = make_float4(0.f, 0.f, 0.f, 0.f);

    int beg = rowptr[node], end = rowptr[node + 1];
    int deg = end - beg;
    for (int j0 = 0; j0 < deg; j0 += 64) {
        int j = j0 + lane;
        int cj = 0; float wj = 0.f;
        if (j < deg) { cj = col[beg + j]; wj = wnorm[beg + j]; }
        int lim = deg - j0; if (lim > 64) lim = 64;
        for (int jj = 0; jj < lim; jj += 8) {
            int sidx[8]; float sw[8];
            #pragma unroll
            for (int q = 0; q < 8; ++q) {
                sidx[q] = __shfl(cj, jj + q);
                sw[q]   = __shfl(wj, jj + q);
            }
            float4 v0[8], v1[8];
            #pragma unroll
            for (int q = 0; q < 8; ++q) {
                const float* r = pre + (size_t)sidx[q] * DIM;
                v0[q] = *reinterpret_cast<const float4*>(r + c0);
                v1[q] = *reinterpret_cast<const float4*>(r + c1);
            }
            #pragma unroll
            for (int q = 0; q < 8; q += 2) {
                FMA4(s0, sw[q], v0[q]);     FMA4(s1, sw[q], v1[q]);
                FMA4(t0, sw[q+1], v0[q+1]); FMA4(t1, sw[q+1], v1[q+1]);
            }
        }
    }
    s0.x += t0.x; s0.y += t0.y; s0.z += t0.z; s0.w += t0.w;
    s1.x += t1.x; s1.y += t1.y; s1.z += t1.z; s1.w += t1.w;

    if (!SPLIT) {
        float* orow = outf + (size_t)node * DIM;
        *reinterpret_cast<float4*>(orow + c0) = s0;
        *reinterpret_cast<float4*>(orow + c1) = s1;
    } else {
        ush4 h0, l0, h1, l1;
        split1(s0.x, h0.x, l0.x); split1(s0.y, h0.y, l0.y);
        split1(s0.z, h0.z, l0.z); split1(s0.w, h0.w, l0.w);
        split1(s1.x, h1.x, l1.x); split1(s1.y, h1.y, l1.y);
        split1(s1.z, h1.z, l1.z); split1(s1.w, h1.w, l1.w);
        size_t base = (size_t)node * DIM;
        *reinterpret_cast<ush4*>(oh + base + c0) = h0;
        *reinterpret_cast<ush4*>(ol + base + c0) = l0;
        *reinterpret_cast<ush4*>(oh + base + c1) = h1;
        *reinterpret_cast<ush4*>(ol + base + c1) = l1;
    }
}

// ---------------- pool: SP[0:1000] = A2 rsu rows; SP[1000:2000] = seg-mean of A2 veh ----
__global__ __launch_bounds__(128) void k_pool_sp(const float* __restrict__ A2,
                                                 const int* __restrict__ seg,
                                                 float* __restrict__ SP,
                                                 float* __restrict__ bscale) {
    int s = blockIdx.x;            // 0..999
    int c = threadIdx.x * 4;       // 0..508
    float4 r = *reinterpret_cast<const float4*>(A2 + (size_t)s * DIM + c);
    *reinterpret_cast<float4*>(SP + (size_t)s * DIM + c) = r;

    int beg = seg[s], end = seg[s + 1];
    float4 acc = make_float4(0.f, 0.f, 0.f, 0.f);
    for (int v = beg; v < end; ++v) {
        float4 t = *reinterpret_cast<const float4*>(A2 + (size_t)(NRSU + v) * DIM + c);
        acc.x += t.x; acc.y += t.y; acc.z += t.z; acc.w += t.w;
    }
    float inv = 1.0f / fmaxf((float)(end - beg), 1.0f);
    acc.x *= inv; acc.y *= inv; acc.z *= inv; acc.w *= inv;
    *reinterpret_cast<float4*>(SP + (size_t)(NRSU + s) * DIM + c) = acc;

    if (threadIdx.x == 0) {
        bscale[s] = 1.0f;
        bscale[NRSU + s] = (end > beg) ? 1.0f : 0.0f;   // empty segment: ref gives exact 0
    }
}

extern "C" void kernel_launch(void* const* d_in, const int* in_sizes, int n_in,
                              void* d_out, int out_size, void* d_ws, size_t ws_size,
                              hipStream_t stream) {
    const float* x     = (const float*)d_in[0];
    const int*   ei    = (const int*)d_in[1];
    const int*   batch = (const int*)d_in[2];
    const float* W1    = (const float*)d_in[3];
    const float* b1    = (const float*)d_in[4];
    const float* W2    = (const float*)d_in[5];
    const float* b2    = (const float*)d_in[6];
    float* out = (float*)d_out;

    char* ws = (char*)d_ws;
    const size_t HALF = (size_t)N_NODES * DIM * 2;        // one bf16 plane (51.2 MB)
    // R0: aggregated-x bf16 planes; reused as A2 (fp32) after GEMM1 consumes them
    unsigned short* Axh = (unsigned short*)(ws);
    unsigned short* Axl = (unsigned short*)(ws + HALF);
    float* A2 = (float*)(ws);
    // R1: h1 fp32 (102.4 MB)
    float* h1 = (float*)(ws + 2 * HALF);
    // Small region
    char* p = ws + 4 * HALF;
    float* dinv    = (float*)p;                p += (size_t)N_NODES * 4;
    int*   cnt     = (int*)p;                  p += (size_t)N_NODES * 4;   // reused as fill
    int*   rowptr  = (int*)p;                  p += (size_t)(N_NODES + 4) * 4;
    int*   col     = (int*)p;                  p += (size_t)E_EDGES * 4;
    float* wnorm   = (float*)p;                p += (size_t)E_EDGES * 4;
    int*   bsum    = (int*)p;                  p += 1024;
    int*   seg     = (int*)p;                  p += (size_t)(NRSU + 8) * 4;
    float* SP      = (float*)p;                p += (size_t)2 * NRSU * DIM * 4;
    unsigned short* SPh = (unsigned short*)p;  p += (size_t)2 * NRSU * DIM * 2;
    unsigned short* SPl = (unsigned short*)p;  p += (size_t)2 * NRSU * DIM * 2;
    float* bscale  = (float*)p;                p += (size_t)2 * NRSU * 4;
    unsigned short* W1h = (unsigned short*)p;  p += (size_t)DIM * DIM * 2;
    unsigned short* W1l = (unsigned short*)p;  p += (size_t)DIM * DIM * 2;
    unsigned short* W2h = (unsigned short*)p;  p += (size_t)DIM * DIM * 2;
    unsigned short* W2l = (unsigned short*)p;  p += (size_t)DIM * DIM * 2;

    dim3 blk(256);
    const int gN = (N_NODES + 255) / 256;
    const int gE = (E_EDGES + 255) / 256;
    const int gV = (NVEH + 255) / 256;

    // ---- CSR build + norm + weight prep ----
    k_zero_int <<<gN, blk, 0, stream>>>(cnt, N_NODES);
    k_count    <<<gE, blk, 0, stream>>>(ei + E_EDGES, cnt);
    k_scan1    <<<gN, blk, 0, stream>>>(cnt, rowptr, bsum);
    k_scan2    <<<1,  blk, 0, stream>>>(bsum);
    k_scan3    <<<gN, blk, 0, stream>>>(rowptr, bsum, cnt, dinv);
    k_fill     <<<gE, blk, 0, stream>>>(ei, rowptr, cnt, col, dinv, wnorm);
    k_segbounds<<<gV, blk, 0, stream>>>(batch, seg);
    k_wsplit   <<<dim3(DIM, 2), blk, 0, stream>>>(W1, W2, W1h, W1l, W2h, W2l);

    // ---- layer 1 (reordered): Ax = S*x (split epilogue); h1 = relu(Ax@W1 + b1) ----
    k_gather<true><<<(N_NODES + 3) / 4, blk, 0, stream>>>(rowptr, col, wnorm, dinv, x, nullptr, Axh, Axl);
    const int NWG1 = ((N_NODES + 127) / 128) * 4;   // 1564
    k_gemm_mfma<2><<<NWG1, blk, 0, stream>>>(Axh, Axl, W1h, W1l, h1, N_NODES, b1, nullptr);

    // ---- layer 2: A2 = S*h1; pool; [A2_rsu; P] @ W2 + b2*bscale -> out ----
    k_gather<false><<<(N_NODES + 3) / 4, blk, 0, stream>>>(rowptr, col, wnorm, dinv, h1, A2, nullptr, nullptr);
    k_pool_sp<<<NRSU, dim3(128), 0, stream>>>(A2, seg, SP, bscale);
    k_split  <<<(2 * NRSU * DIM / 4) / 256, blk, 0, stream>>>(SP, SPh, SPl);
    const int NWG2 = ((2 * NRSU + 127) / 128) * 4;  // 64
    k_gemm_mfma<1><<<NWG2, blk, 0, stream>>>(SPh, SPl, W2h, W2l, out, 2 * NRSU, b2, bscale);
}

// Round 11
// 405.485 us; speedup vs baseline: 1.7304x; 1.2869x over previous
//
#include <hip/hip_runtime.h>

#define N_NODES 50000
#define E_EDGES 400000
#define DIM     512
#define NRSU    1000
#define NVEH    (N_NODES - NRSU)
#define NB_SCAN 196           // ceil(50000/256)

typedef __attribute__((ext_vector_type(8))) __bf16 bf16x8;
typedef __attribute__((ext_vector_type(4))) float  f32x4;
typedef __attribute__((ext_vector_type(8))) unsigned short ush8v;

struct __align__(8) ush4 { unsigned short x, y, z, w; };

// ---------- bf16 helpers (RNE) ----------
__device__ __forceinline__ unsigned short f2bf_rne(float x) {
    unsigned u = __float_as_uint(x);
    unsigned r = u + 0x7fff + ((u >> 16) & 1);
    return (unsigned short)(r >> 16);
}
__device__ __forceinline__ float bf2f(unsigned short b) {
    return __uint_as_float((unsigned)b << 16);
}
__device__ __forceinline__ void split1(float v, unsigned short& h, unsigned short& l) {
    h = f2bf_rne(v);
    l = f2bf_rne(v - bf2f(h));
}
// unpack 8 packed bf16 (uint4) -> 8 floats
__device__ __forceinline__ void cvt8(uint4 v, float* f) {
    f[0] = __uint_as_float(v.x << 16); f[1] = __uint_as_float(v.x & 0xffff0000u);
    f[2] = __uint_as_float(v.y << 16); f[3] = __uint_as_float(v.y & 0xffff0000u);
    f[4] = __uint_as_float(v.z << 16); f[5] = __uint_as_float(v.z & 0xffff0000u);
    f[6] = __uint_as_float(v.w << 16); f[7] = __uint_as_float(v.w & 0xffff0000u);
}

// ---------- async global->LDS (16B per lane) ----------
typedef __attribute__((address_space(1))) const unsigned char ga_u8;
typedef __attribute__((address_space(3))) unsigned char la_u8;
__device__ __forceinline__ void gload16(const void* g, void* l) {
    __builtin_amdgcn_global_load_lds((ga_u8*)g, (la_u8*)l, 16, 0, 0);
}

// ---------------- zero int array ----------------
__global__ void k_zero_int(int* __restrict__ p, int n) {
    int i = blockIdx.x * 256 + threadIdx.x;
    if (i < n) p[i] = 0;
}

// ---------------- fp32 -> bf16 round (x pre-round) ----------------
__global__ void k_tobf16(const float* __restrict__ in, unsigned short* __restrict__ out) {
    size_t i = ((size_t)blockIdx.x * 256 + threadIdx.x) * 8;
    float4 a = *reinterpret_cast<const float4*>(in + i);
    float4 b = *reinterpret_cast<const float4*>(in + i + 4);
    ush8v o;
    o[0] = f2bf_rne(a.x); o[1] = f2bf_rne(a.y); o[2] = f2bf_rne(a.z); o[3] = f2bf_rne(a.w);
    o[4] = f2bf_rne(b.x); o[5] = f2bf_rne(b.y); o[6] = f2bf_rne(b.z); o[7] = f2bf_rne(b.w);
    *reinterpret_cast<ush8v*>(out + i) = o;
}

// ---------------- in-degree count ----------------
__global__ void k_count(const int* __restrict__ dst, int* __restrict__ cnt) {
    int e = blockIdx.x * 256 + threadIdx.x;
    if (e < E_EDGES) atomicAdd(&cnt[dst[e]], 1);
}

// ---------------- block-wise exclusive scan ----------------
__global__ __launch_bounds__(256) void k_scan1(const int* __restrict__ cnt,
                                               int* __restrict__ rowptr,
                                               int* __restrict__ bsum) {
    __shared__ int sh[256];
    int tid = threadIdx.x;
    int i = blockIdx.x * 256 + tid;
    int v = (i < N_NODES) ? cnt[i] : 0;
    sh[tid] = v;
    __syncthreads();
    #pragma unroll
    for (int off = 1; off < 256; off <<= 1) {
        int t = (tid >= off) ? sh[tid - off] : 0;
        __syncthreads();
        sh[tid] += t;
        __syncthreads();
    }
    if (i < N_NODES) rowptr[i] = sh[tid] - v;
    if (tid == 255) bsum[blockIdx.x] = sh[255];
}

__global__ __launch_bounds__(256) void k_scan2(int* __restrict__ bsum) {
    __shared__ int sh[256];
    int tid = threadIdx.x;
    int v = (tid < NB_SCAN) ? bsum[tid] : 0;
    sh[tid] = v;
    __syncthreads();
    #pragma unroll
    for (int off = 1; off < 256; off <<= 1) {
        int t = (tid >= off) ? sh[tid - off] : 0;
        __syncthreads();
        sh[tid] += t;
        __syncthreads();
    }
    if (tid < NB_SCAN) bsum[tid] = sh[tid] - v;
}

// scan finalize + dinv + zero fill counters (merged)
__global__ void k_scan3(int* __restrict__ rowptr, const int* __restrict__ bsum,
                        int* __restrict__ cntfill, float* __restrict__ dinv) {
    int i = blockIdx.x * 256 + threadIdx.x;
    if (i < N_NODES) {
        rowptr[i] += bsum[blockIdx.x];
        int c = cntfill[i];
        dinv[i] = rsqrtf((float)c + 1.0f);   // self-loop
        cntfill[i] = 0;                      // becomes fill counter
    }
    if (i == 0) rowptr[N_NODES] = E_EDGES;
}

// ---------------- CSR fill (+ precomputed edge weights) ----------------
__global__ void k_fill(const int* __restrict__ ei, const int* __restrict__ rowptr,
                       int* __restrict__ fill, int* __restrict__ col,
                       const float* __restrict__ dinv, float* __restrict__ wnorm) {
    int e = blockIdx.x * 256 + threadIdx.x;
    if (e >= E_EDGES) return;
    int s = ei[e];
    int d = ei[E_EDGES + e];
    int p = atomicAdd(&fill[d], 1);
    int idx = rowptr[d] + p;
    col[idx] = s;
    wnorm[idx] = dinv[s] * dinv[d];
}

// ---------------- segment boundaries (batch monotone over vehicles) ----
__global__ void k_segbounds(const int* __restrict__ batch, int* __restrict__ seg) {
    int v = blockIdx.x * 256 + threadIdx.x;
    if (v >= NVEH) return;
    int b = batch[NRSU + v];
    if (v == 0) {
        for (int s = 0; s <= b; ++s) seg[s] = 0;
    } else {
        int bp = batch[NRSU + v - 1];
        for (int s = bp + 1; s <= b; ++s) seg[s] = v;
    }
    if (v == NVEH - 1) {
        for (int s = b + 1; s <= NRSU; ++s) seg[s] = NVEH;
    }
}

// ---------------- both W [K][N] -> W^T split bf16 hi/lo [N][K] ----------------
__global__ void k_wsplit(const float* __restrict__ W1, const float* __restrict__ W2,
                         unsigned short* __restrict__ W1h, unsigned short* __restrict__ W1l,
                         unsigned short* __restrict__ W2h, unsigned short* __restrict__ W2l) {
    const float* W = blockIdx.y ? W2 : W1;
    unsigned short* Wh = blockIdx.y ? W2h : W1h;
    unsigned short* Wl = blockIdx.y ? W2l : W1l;
    int n = blockIdx.x;
    for (int k = threadIdx.x; k < DIM; k += 256) {
        float v = W[(size_t)k * DIM + n];
        unsigned short h, l;
        split1(v, h, l);
        Wh[(size_t)n * DIM + k] = h;
        Wl[(size_t)n * DIM + k] = l;
    }
}

// ---------------- fp32 -> bf16 hi/lo split (vector pass, SP only) -------
__global__ void k_split(const float* __restrict__ in,
                        unsigned short* __restrict__ hi,
                        unsigned short* __restrict__ lo) {
    size_t i = ((size_t)blockIdx.x * 256 + threadIdx.x) * 4;
    float4 v = *reinterpret_cast<const float4*>(in + i);
    ush4 h, l;
    split1(v.x, h.x, l.x);
    split1(v.y, h.y, l.y);
    split1(v.z, h.z, l.z);
    split1(v.w, h.w, l.w);
    *reinterpret_cast<ush4*>(hi + i) = h;
    *reinterpret_cast<ush4*>(lo + i) = l;
}

// ---------------- split-bf16 MFMA GEMM with XOR-swizzled LDS ----------------
// MODE 1: M=2000 "[rsu; pooled]" rows -> out (fp32) with concat layout, + b[col]*bscale[row]
// MODE 2: Cb[M x 512] (bf16) = relu(A@B + bias), 1-D grid with bijective XCD remap
template<int MODE>
__global__ __launch_bounds__(256) void k_gemm_mfma(const unsigned short* __restrict__ Ah,
                                                   const unsigned short* __restrict__ Al,
                                                   const unsigned short* __restrict__ BhT,
                                                   const unsigned short* __restrict__ BlT,
                                                   float* __restrict__ C,
                                                   unsigned short* __restrict__ Cb, int M,
                                                   const float* __restrict__ bias,
                                                   const float* __restrict__ bscale) {
    const int BM = 128, BN = 128, BK = 32;
    __shared__ unsigned short sAh[BM * BK];
    __shared__ unsigned short sAl[BM * BK];
    __shared__ unsigned short sBh[BN * BK];
    __shared__ unsigned short sBl[BN * BK];

    int tid = threadIdx.x;
    int wv = tid >> 6;
    int ln = tid & 63;

    int wgid;
    if (MODE == 2) {
        // bijective XCD-chunk remap: nwg = 1564 = 8*195 + 4
        const int q = 195, r = 4;
        int id = blockIdx.x;
        int xcd = id & 7, idx = id >> 3;
        wgid = (xcd < r ? xcd * (q + 1) : r * (q + 1) + (xcd - r) * q) + idx;
    } else {
        wgid = blockIdx.x;
    }
    int col0 = (wgid & 3) * BN;        // col fastest: 4 col-tiles share A row-panel
    int row0 = (wgid >> 2) * BM;

    int wr = wv >> 1, wc = wv & 1;     // 2x2 waves, each 64x64
    int fr = ln & 15;
    int ks16 = ln >> 4;                // k-chunk 0..3

    f32x4 zero = {0.f, 0.f, 0.f, 0.f};
    f32x4 acc[4][4];
    #pragma unroll
    for (int m = 0; m < 4; ++m)
        #pragma unroll
        for (int n = 0; n < 4; ++n) acc[m][n] = zero;

    for (int k0 = 0; k0 < DIM; k0 += BK) {
        __syncthreads();
        #pragma unroll
        for (int p = 0; p < 2; ++p) {
            int idx = p * 256 + tid;           // (row, slot): row = idx>>2, slot = idx&3
            int r = idx >> 2;
            int slot = idx & 3;
            int c = ((slot ^ (r & 3)) << 3);   // pre-swizzled global k-chunk
            int arow = row0 + r; if (arow > M - 1) arow = M - 1;
            size_t aoff = (size_t)arow * DIM + k0 + c;
            size_t boff = (size_t)(col0 + r) * DIM + k0 + c;
            int lbyte = p * 4096 + wv * 1024;  // linear wave-uniform LDS dest
            gload16(Ah + aoff, (char*)sAh + lbyte);
            gload16(Al + aoff, (char*)sAl + lbyte);
            gload16(BhT + boff, (char*)sBh + lbyte);
            gload16(BlT + boff, (char*)sBl + lbyte);
        }
        __syncthreads();

        bf16x8 ah[4], al[4], bh[4], bl[4];
        #pragma unroll
        for (int m = 0; m < 4; ++m) {
            int r = wr * 64 + m * 16 + fr;
            int e = r * BK + ((ks16 ^ (r & 3)) << 3);
            ah[m] = *reinterpret_cast<const bf16x8*>(&sAh[e]);
            al[m] = *reinterpret_cast<const bf16x8*>(&sAl[e]);
        }
        #pragma unroll
        for (int n = 0; n < 4; ++n) {
            int r = wc * 64 + n * 16 + fr;
            int e = r * BK + ((ks16 ^ (r & 3)) << 3);
            bh[n] = *reinterpret_cast<const bf16x8*>(&sBh[e]);
            bl[n] = *reinterpret_cast<const bf16x8*>(&sBl[e]);
        }
        #pragma unroll
        for (int m = 0; m < 4; ++m)
            #pragma unroll
            for (int n = 0; n < 4; ++n) {
                acc[m][n] = __builtin_amdgcn_mfma_f32_16x16x32_bf16(ah[m], bh[n], acc[m][n], 0, 0, 0);
                acc[m][n] = __builtin_amdgcn_mfma_f32_16x16x32_bf16(al[m], bh[n], acc[m][n], 0, 0, 0);
                acc[m][n] = __builtin_amdgcn_mfma_f32_16x16x32_bf16(ah[m], bl[n], acc[m][n], 0, 0, 0);
            }
    }

    int rbase = row0 + wr * 64 + (ln >> 4) * 4;
    int cbase = col0 + wc * 64 + (ln & 15);
    #pragma unroll
    for (int m = 0; m < 4; ++m)
        #pragma unroll
        for (int r4 = 0; r4 < 4; ++r4) {
            int row = rbase + m * 16 + r4;
            if (row < M) {
                if (MODE == 2) {
                    #pragma unroll
                    for (int n = 0; n < 4; ++n) {
                        int cc = cbase + n * 16;
                        Cb[(size_t)row * DIM + cc] =
                            f2bf_rne(fmaxf(acc[m][n][r4] + bias[cc], 0.f));
                    }
                } else {
                    float bs = bscale[row];
                    float* dst = (row < NRSU) ? (C + (size_t)row * 1024)
                                              : (C + (size_t)(row - NRSU) * 1024 + 512);
                    #pragma unroll
                    for (int n = 0; n < 4; ++n) {
                        int cc = cbase + n * 16;
                        dst[cc] = acc[m][n][r4] + bias[cc] * bs;
                    }
                }
            }
        }
}

// ---------------- CSR gather on bf16 rows: out = S_norm * pre ----------------
// SPLIT=1: write hi/lo bf16 planes (GEMM input). SPLIT=0: write fp32.
template<bool SPLIT>
__global__ __launch_bounds__(256) void k_gather_bf(const int* __restrict__ rowptr,
                                                   const int* __restrict__ col,
                                                   const float* __restrict__ wnorm,
                                                   const float* __restrict__ dinv,
                                                   const unsigned short* __restrict__ pre,
                                                   float* __restrict__ outf,
                                                   unsigned short* __restrict__ oh,
                                                   unsigned short* __restrict__ ol) {
    int node = blockIdx.x * 4 + (threadIdx.x >> 6);
    if (node >= N_NODES) return;
    int lane = threadIdx.x & 63;
    int c = lane * 8;                   // 8 consecutive columns per lane

    float di = dinv[node];
    float w0 = di * di;
    float s[8], t[8];
    {
        uint4 sv = *reinterpret_cast<const uint4*>(pre + (size_t)node * DIM + c);
        float fa[8]; cvt8(sv, fa);
        #pragma unroll
        for (int i = 0; i < 8; ++i) { s[i] = w0 * fa[i]; t[i] = 0.f; }
    }

    int beg = rowptr[node], end = rowptr[node + 1];
    int deg = end - beg;
    for (int j0 = 0; j0 < deg; j0 += 64) {
        int j = j0 + lane;
        int cj = 0; float wj = 0.f;
        if (j < deg) { cj = col[beg + j]; wj = wnorm[beg + j]; }
        int lim = deg - j0; if (lim > 64) lim = 64;
        // branchless chunks of 8: lanes beyond lim carry w=0
        for (int jj = 0; jj < lim; jj += 8) {
            int sidx[8]; float sw[8];
            #pragma unroll
            for (int q = 0; q < 8; ++q) {
                sidx[q] = __shfl(cj, jj + q);
                sw[q]   = __shfl(wj, jj + q);
            }
            uint4 v[8];
            #pragma unroll
            for (int q = 0; q < 8; ++q)
                v[q] = *reinterpret_cast<const uint4*>(pre + (size_t)sidx[q] * DIM + c);
            #pragma unroll
            for (int q = 0; q < 8; ++q) {
                float f[8]; cvt8(v[q], f);
                if ((q & 1) == 0) {
                    #pragma unroll
                    for (int i = 0; i < 8; ++i) s[i] = fmaf(sw[q], f[i], s[i]);
                } else {
                    #pragma unroll
                    for (int i = 0; i < 8; ++i) t[i] = fmaf(sw[q], f[i], t[i]);
                }
            }
        }
    }
    #pragma unroll
    for (int i = 0; i < 8; ++i) s[i] += t[i];

    if (!SPLIT) {
        float* orow = outf + (size_t)node * DIM + c;
        *reinterpret_cast<float4*>(orow)     = make_float4(s[0], s[1], s[2], s[3]);
        *reinterpret_cast<float4*>(orow + 4) = make_float4(s[4], s[5], s[6], s[7]);
    } else {
        ush8v h, l;
        #pragma unroll
        for (int i = 0; i < 8; ++i) {
            unsigned short hh, ll;
            split1(s[i], hh, ll);
            h[i] = hh; l[i] = ll;
        }
        size_t base = (size_t)node * DIM + c;
        *reinterpret_cast<ush8v*>(oh + base) = h;
        *reinterpret_cast<ush8v*>(ol + base) = l;
    }
}

// ---------------- pool: SP[0:1000] = A2 rsu rows; SP[1000:2000] = seg-mean ----
__global__ __launch_bounds__(128) void k_pool_sp(const float* __restrict__ A2,
                                                 const int* __restrict__ seg,
                                                 float* __restrict__ SP,
                                                 float* __restrict__ bscale) {
    int s = blockIdx.x;            // 0..999
    int c = threadIdx.x * 4;       // 0..508
    float4 r = *reinterpret_cast<const float4*>(A2 + (size_t)s * DIM + c);
    *reinterpret_cast<float4*>(SP + (size_t)s * DIM + c) = r;

    int beg = seg[s], end = seg[s + 1];
    float4 acc = make_float4(0.f, 0.f, 0.f, 0.f);
    for (int v = beg; v < end; ++v) {
        float4 t = *reinterpret_cast<const float4*>(A2 + (size_t)(NRSU + v) * DIM + c);
        acc.x += t.x; acc.y += t.y; acc.z += t.z; acc.w += t.w;
    }
    float inv = 1.0f / fmaxf((float)(end - beg), 1.0f);
    acc.x *= inv; acc.y *= inv; acc.z *= inv; acc.w *= inv;
    *reinterpret_cast<float4*>(SP + (size_t)(NRSU + s) * DIM + c) = acc;

    if (threadIdx.x == 0) {
        bscale[s] = 1.0f;
        bscale[NRSU + s] = (end > beg) ? 1.0f : 0.0f;   // empty segment: ref gives exact 0
    }
}

extern "C" void kernel_launch(void* const* d_in, const int* in_sizes, int n_in,
                              void* d_out, int out_size, void* d_ws, size_t ws_size,
                              hipStream_t stream) {
    const float* x     = (const float*)d_in[0];
    const int*   ei    = (const int*)d_in[1];
    const int*   batch = (const int*)d_in[2];
    const float* W1    = (const float*)d_in[3];
    const float* b1    = (const float*)d_in[4];
    const float* W2    = (const float*)d_in[5];
    const float* b2    = (const float*)d_in[6];
    float* out = (float*)d_out;

    char* ws = (char*)d_ws;
    const size_t HALF = (size_t)N_NODES * DIM * 2;        // one bf16 plane (51.2 MB)
    // R0: Ax hi/lo bf16 planes; reused as A2 (fp32) after GEMM1 consumes them
    unsigned short* Axh = (unsigned short*)(ws);
    unsigned short* Axl = (unsigned short*)(ws + HALF);
    float* A2 = (float*)(ws);
    // R1: h1 bf16 plane | x bf16 plane
    unsigned short* h1b = (unsigned short*)(ws + 2 * HALF);
    unsigned short* xb  = (unsigned short*)(ws + 3 * HALF);
    // Small region
    char* p = ws + 4 * HALF;
    float* dinv    = (float*)p;                p += (size_t)N_NODES * 4;
    int*   cnt     = (int*)p;                  p += (size_t)N_NODES * 4;   // reused as fill
    int*   rowptr  = (int*)p;                  p += (size_t)(N_NODES + 4) * 4;
    int*   col     = (int*)p;                  p += (size_t)E_EDGES * 4;
    float* wnorm   = (float*)p;                p += (size_t)E_EDGES * 4;
    int*   bsum    = (int*)p;                  p += 1024;
    int*   seg     = (int*)p;                  p += (size_t)(NRSU + 8) * 4;
    float* SP      = (float*)p;                p += (size_t)2 * NRSU * DIM * 4;
    unsigned short* SPh = (unsigned short*)p;  p += (size_t)2 * NRSU * DIM * 2;
    unsigned short* SPl = (unsigned short*)p;  p += (size_t)2 * NRSU * DIM * 2;
    float* bscale  = (float*)p;                p += (size_t)2 * NRSU * 4;
    unsigned short* W1h = (unsigned short*)p;  p += (size_t)DIM * DIM * 2;
    unsigned short* W1l = (unsigned short*)p;  p += (size_t)DIM * DIM * 2;
    unsigned short* W2h = (unsigned short*)p;  p += (size_t)DIM * DIM * 2;
    unsigned short* W2l = (unsigned short*)p;  p += (size_t)DIM * DIM * 2;

    dim3 blk(256);
    const int gN = (N_NODES + 255) / 256;
    const int gE = (E_EDGES + 255) / 256;
    const int gV = (NVEH + 255) / 256;

    // ---- CSR build + norm + weight prep + x pre-round ----
    k_zero_int <<<gN, blk, 0, stream>>>(cnt, N_NODES);
    k_count    <<<gE, blk, 0, stream>>>(ei + E_EDGES, cnt);
    k_scan1    <<<gN, blk, 0, stream>>>(cnt, rowptr, bsum);
    k_scan2    <<<1,  blk, 0, stream>>>(bsum);
    k_scan3    <<<gN, blk, 0, stream>>>(rowptr, bsum, cnt, dinv);
    k_fill     <<<gE, blk, 0, stream>>>(ei, rowptr, cnt, col, dinv, wnorm);
    k_segbounds<<<gV, blk, 0, stream>>>(batch, seg);
    k_wsplit   <<<dim3(DIM, 2), blk, 0, stream>>>(W1, W2, W1h, W1l, W2h, W2l);
    k_tobf16   <<<(int)((size_t)N_NODES * DIM / 8 / 256), blk, 0, stream>>>(x, xb);

    // ---- layer 1: Ax = S*xb (split epilogue); h1b = bf16(relu(Ax@W1 + b1)) ----
    k_gather_bf<true><<<(N_NODES + 3) / 4, blk, 0, stream>>>(rowptr, col, wnorm, dinv, xb,
                                                             nullptr, Axh, Axl);
    const int NWG1 = ((N_NODES + 127) / 128) * 4;   // 1564
    k_gemm_mfma<2><<<NWG1, blk, 0, stream>>>(Axh, Axl, W1h, W1l, nullptr, h1b, N_NODES, b1, nullptr);

    // ---- layer 2: A2 = S*h1b (fp32); pool; [A2_rsu; P] @ W2 + b2*bscale -> out ----
    k_gather_bf<false><<<(N_NODES + 3) / 4, blk, 0, stream>>>(rowptr, col, wnorm, dinv, h1b,
                                                              A2, nullptr, nullptr);
    k_pool_sp<<<NRSU, dim3(128), 0, stream>>>(A2, seg, SP, bscale);
    k_split  <<<(2 * NRSU * DIM / 4) / 256, blk, 0, stream>>>(SP, SPh, SPl);
    const int NWG2 = ((2 * NRSU + 127) / 128) * 4;  // 64
    k_gemm_mfma<1><<<NWG2, blk, 0, stream>>>(SPh, SPl, W2h, W2l, out, nullptr, 2 * NRSU, b2, bscale);
}

// Round 12
// 397.957 us; speedup vs baseline: 1.7631x; 1.0189x over previous
//
#include <hip/hip_runtime.h>

#define N_NODES 50000
#define E_EDGES 400000
#define DIM     512
#define NRSU    1000
#define NVEH    (N_NODES - NRSU)
#define NB_SCAN 196           // ceil(50000/256)

typedef __attribute__((ext_vector_type(8))) __bf16 bf16x8;
typedef __attribute__((ext_vector_type(4))) float  f32x4;
typedef __attribute__((ext_vector_type(8))) unsigned short ush8v;

struct __align__(8) ush4 { unsigned short x, y, z, w; };

// ---------- bf16 helpers (RNE) ----------
__device__ __forceinline__ unsigned short f2bf_rne(float x) {
    unsigned u = __float_as_uint(x);
    unsigned r = u + 0x7fff + ((u >> 16) & 1);
    return (unsigned short)(r >> 16);
}
__device__ __forceinline__ float bf2f(unsigned short b) {
    return __uint_as_float((unsigned)b << 16);
}
__device__ __forceinline__ void split1(float v, unsigned short& h, unsigned short& l) {
    h = f2bf_rne(v);
    l = f2bf_rne(v - bf2f(h));
}
// unpack 8 packed bf16 (uint4) -> 8 floats
__device__ __forceinline__ void cvt8(uint4 v, float* f) {
    f[0] = __uint_as_float(v.x << 16); f[1] = __uint_as_float(v.x & 0xffff0000u);
    f[2] = __uint_as_float(v.y << 16); f[3] = __uint_as_float(v.y & 0xffff0000u);
    f[4] = __uint_as_float(v.z << 16); f[5] = __uint_as_float(v.z & 0xffff0000u);
    f[6] = __uint_as_float(v.w << 16); f[7] = __uint_as_float(v.w & 0xffff0000u);
}

// ---------- async global->LDS (16B per lane) ----------
typedef __attribute__((address_space(1))) const unsigned char ga_u8;
typedef __attribute__((address_space(3))) unsigned char la_u8;
__device__ __forceinline__ void gload16(const void* g, void* l) {
    __builtin_amdgcn_global_load_lds((ga_u8*)g, (la_u8*)l, 16, 0, 0);
}

// ---------------- zero int array ----------------
__global__ void k_zero_int(int* __restrict__ p, int n) {
    int i = blockIdx.x * 256 + threadIdx.x;
    if (i < n) p[i] = 0;
}

// ---------------- fp32 -> bf16 round (x pre-round) ----------------
__global__ void k_tobf16(const float* __restrict__ in, unsigned short* __restrict__ out) {
    size_t i = ((size_t)blockIdx.x * 256 + threadIdx.x) * 8;
    float4 a = *reinterpret_cast<const float4*>(in + i);
    float4 b = *reinterpret_cast<const float4*>(in + i + 4);
    ush8v o;
    o[0] = f2bf_rne(a.x); o[1] = f2bf_rne(a.y); o[2] = f2bf_rne(a.z); o[3] = f2bf_rne(a.w);
    o[4] = f2bf_rne(b.x); o[5] = f2bf_rne(b.y); o[6] = f2bf_rne(b.z); o[7] = f2bf_rne(b.w);
    *reinterpret_cast<ush8v*>(out + i) = o;
}

// ---------------- in-degree count ----------------
__global__ void k_count(const int* __restrict__ dst, int* __restrict__ cnt) {
    int e = blockIdx.x * 256 + threadIdx.x;
    if (e < E_EDGES) atomicAdd(&cnt[dst[e]], 1);
}

// ---------------- block-wise exclusive scan ----------------
__global__ __launch_bounds__(256) void k_scan1(const int* __restrict__ cnt,
                                               int* __restrict__ rowptr,
                                               int* __restrict__ bsum) {
    __shared__ int sh[256];
    int tid = threadIdx.x;
    int i = blockIdx.x * 256 + tid;
    int v = (i < N_NODES) ? cnt[i] : 0;
    sh[tid] = v;
    __syncthreads();
    #pragma unroll
    for (int off = 1; off < 256; off <<= 1) {
        int t = (tid >= off) ? sh[tid - off] : 0;
        __syncthreads();
        sh[tid] += t;
        __syncthreads();
    }
    if (i < N_NODES) rowptr[i] = sh[tid] - v;
    if (tid == 255) bsum[blockIdx.x] = sh[255];
}

__global__ __launch_bounds__(256) void k_scan2(int* __restrict__ bsum) {
    __shared__ int sh[256];
    int tid = threadIdx.x;
    int v = (tid < NB_SCAN) ? bsum[tid] : 0;
    sh[tid] = v;
    __syncthreads();
    #pragma unroll
    for (int off = 1; off < 256; off <<= 1) {
        int t = (tid >= off) ? sh[tid - off] : 0;
        __syncthreads();
        sh[tid] += t;
        __syncthreads();
    }
    if (tid < NB_SCAN) bsum[tid] = sh[tid] - v;
}

// scan finalize + dinv + zero fill counters (merged)
__global__ void k_scan3(int* __restrict__ rowptr, const int* __restrict__ bsum,
                        int* __restrict__ cntfill, float* __restrict__ dinv) {
    int i = blockIdx.x * 256 + threadIdx.x;
    if (i < N_NODES) {
        rowptr[i] += bsum[blockIdx.x];
        int c = cntfill[i];
        dinv[i] = rsqrtf((float)c + 1.0f);   // self-loop
        cntfill[i] = 0;                      // becomes fill counter
    }
    if (i == 0) rowptr[N_NODES] = E_EDGES;
}

// ---------------- CSR fill (+ precomputed edge weights) ----------------
__global__ void k_fill(const int* __restrict__ ei, const int* __restrict__ rowptr,
                       int* __restrict__ fill, int* __restrict__ col,
                       const float* __restrict__ dinv, float* __restrict__ wnorm) {
    int e = blockIdx.x * 256 + threadIdx.x;
    if (e >= E_EDGES) return;
    int s = ei[e];
    int d = ei[E_EDGES + e];
    int p = atomicAdd(&fill[d], 1);
    int idx = rowptr[d] + p;
    col[idx] = s;
    wnorm[idx] = dinv[s] * dinv[d];
}

// ---------------- segment boundaries (batch monotone over vehicles) ----
__global__ void k_segbounds(const int* __restrict__ batch, int* __restrict__ seg) {
    int v = blockIdx.x * 256 + threadIdx.x;
    if (v >= NVEH) return;
    int b = batch[NRSU + v];
    if (v == 0) {
        for (int s = 0; s <= b; ++s) seg[s] = 0;
    } else {
        int bp = batch[NRSU + v - 1];
        for (int s = bp + 1; s <= b; ++s) seg[s] = v;
    }
    if (v == NVEH - 1) {
        for (int s = b + 1; s <= NRSU; ++s) seg[s] = NVEH;
    }
}

// ---------------- both W [K][N] -> W^T split bf16 hi/lo [N][K] ----------------
__global__ void k_wsplit(const float* __restrict__ W1, const float* __restrict__ W2,
                         unsigned short* __restrict__ W1h, unsigned short* __restrict__ W1l,
                         unsigned short* __restrict__ W2h, unsigned short* __restrict__ W2l) {
    const float* W = blockIdx.y ? W2 : W1;
    unsigned short* Wh = blockIdx.y ? W2h : W1h;
    unsigned short* Wl = blockIdx.y ? W2l : W1l;
    int n = blockIdx.x;
    for (int k = threadIdx.x; k < DIM; k += 256) {
        float v = W[(size_t)k * DIM + n];
        unsigned short h, l;
        split1(v, h, l);
        Wh[(size_t)n * DIM + k] = h;
        Wl[(size_t)n * DIM + k] = l;
    }
}

// ---------------- split-bf16 MFMA GEMM with XOR-swizzled LDS ----------------
// Swizzle: 16B-slot s at row r holds k-chunk (s ^ ((r>>1)&3)) -> bank-granule
// (r*4+s) mod 8 hits each value exactly twice per 16-lane group (2-way = free).
// MODE 1: M=2000 "[rsu; pooled]" rows -> out (fp32) concat layout, + b[col]*bscale[row]
// MODE 2: Cb[M x 512] (bf16) = relu(A@B + bias), 1-D grid with bijective XCD remap
template<int MODE>
__global__ __launch_bounds__(256) void k_gemm_mfma(const unsigned short* __restrict__ Ah,
                                                   const unsigned short* __restrict__ Al,
                                                   const unsigned short* __restrict__ BhT,
                                                   const unsigned short* __restrict__ BlT,
                                                   float* __restrict__ C,
                                                   unsigned short* __restrict__ Cb, int M,
                                                   const float* __restrict__ bias,
                                                   const float* __restrict__ bscale) {
    const int BM = 128, BN = 128, BK = 32;
    __shared__ unsigned short sAh[BM * BK];
    __shared__ unsigned short sAl[BM * BK];
    __shared__ unsigned short sBh[BN * BK];
    __shared__ unsigned short sBl[BN * BK];

    int tid = threadIdx.x;
    int wv = tid >> 6;
    int ln = tid & 63;

    int wgid;
    if (MODE == 2) {
        // bijective XCD-chunk remap: nwg = 1564 = 8*195 + 4
        const int q = 195, r = 4;
        int id = blockIdx.x;
        int xcd = id & 7, idx = id >> 3;
        wgid = (xcd < r ? xcd * (q + 1) : r * (q + 1) + (xcd - r) * q) + idx;
    } else {
        wgid = blockIdx.x;
    }
    int col0 = (wgid & 3) * BN;        // col fastest: 4 col-tiles share A row-panel
    int row0 = (wgid >> 2) * BM;

    int wr = wv >> 1, wc = wv & 1;     // 2x2 waves, each 64x64
    int fr = ln & 15;
    int ks16 = ln >> 4;                // k-chunk 0..3

    f32x4 zero = {0.f, 0.f, 0.f, 0.f};
    f32x4 acc[4][4];
    #pragma unroll
    for (int m = 0; m < 4; ++m)
        #pragma unroll
        for (int n = 0; n < 4; ++n) acc[m][n] = zero;

    for (int k0 = 0; k0 < DIM; k0 += BK) {
        __syncthreads();
        #pragma unroll
        for (int p = 0; p < 2; ++p) {
            int idx = p * 256 + tid;           // (row, slot): row = idx>>2, slot = idx&3
            int r = idx >> 2;
            int slot = idx & 3;
            int c = ((slot ^ ((r >> 1) & 3)) << 3);   // pre-swizzled global k-chunk
            int arow = row0 + r; if (arow > M - 1) arow = M - 1;
            size_t aoff = (size_t)arow * DIM + k0 + c;
            size_t boff = (size_t)(col0 + r) * DIM + k0 + c;
            int lbyte = p * 4096 + wv * 1024;  // linear wave-uniform LDS dest
            gload16(Ah + aoff, (char*)sAh + lbyte);
            gload16(Al + aoff, (char*)sAl + lbyte);
            gload16(BhT + boff, (char*)sBh + lbyte);
            gload16(BlT + boff, (char*)sBl + lbyte);
        }
        __syncthreads();

        bf16x8 ah[4], al[4], bh[4], bl[4];
        #pragma unroll
        for (int m = 0; m < 4; ++m) {
            int r = wr * 64 + m * 16 + fr;
            int e = r * BK + ((ks16 ^ ((r >> 1) & 3)) << 3);
            ah[m] = *reinterpret_cast<const bf16x8*>(&sAh[e]);
            al[m] = *reinterpret_cast<const bf16x8*>(&sAl[e]);
        }
        #pragma unroll
        for (int n = 0; n < 4; ++n) {
            int r = wc * 64 + n * 16 + fr;
            int e = r * BK + ((ks16 ^ ((r >> 1) & 3)) << 3);
            bh[n] = *reinterpret_cast<const bf16x8*>(&sBh[e]);
            bl[n] = *reinterpret_cast<const bf16x8*>(&sBl[e]);
        }
        #pragma unroll
        for (int m = 0; m < 4; ++m)
            #pragma unroll
            for (int n = 0; n < 4; ++n) {
                acc[m][n] = __builtin_amdgcn_mfma_f32_16x16x32_bf16(ah[m], bh[n], acc[m][n], 0, 0, 0);
                acc[m][n] = __builtin_amdgcn_mfma_f32_16x16x32_bf16(al[m], bh[n], acc[m][n], 0, 0, 0);
                acc[m][n] = __builtin_amdgcn_mfma_f32_16x16x32_bf16(ah[m], bl[n], acc[m][n], 0, 0, 0);
            }
    }

    int rbase = row0 + wr * 64 + (ln >> 4) * 4;
    int cbase = col0 + wc * 64 + (ln & 15);
    #pragma unroll
    for (int m = 0; m < 4; ++m)
        #pragma unroll
        for (int r4 = 0; r4 < 4; ++r4) {
            int row = rbase + m * 16 + r4;
            if (row < M) {
                if (MODE == 2) {
                    #pragma unroll
                    for (int n = 0; n < 4; ++n) {
                        int cc = cbase + n * 16;
                        Cb[(size_t)row * DIM + cc] =
                            f2bf_rne(fmaxf(acc[m][n][r4] + bias[cc], 0.f));
                    }
                } else {
                    float bs = bscale[row];
                    float* dst = (row < NRSU) ? (C + (size_t)row * 1024)
                                              : (C + (size_t)(row - NRSU) * 1024 + 512);
                    #pragma unroll
                    for (int n = 0; n < 4; ++n) {
                        int cc = cbase + n * 16;
                        dst[cc] = acc[m][n][r4] + bias[cc] * bs;
                    }
                }
            }
        }
}

// ---------------- CSR gather on bf16 rows: out = S_norm * pre ----------------
// OMODE 1: write hi/lo bf16 planes (GEMM input). OMODE 2: write single bf16 plane.
template<int OMODE>
__global__ __launch_bounds__(256) void k_gather_bf(const int* __restrict__ rowptr,
                                                   const int* __restrict__ col,
                                                   const float* __restrict__ wnorm,
                                                   const float* __restrict__ dinv,
                                                   const unsigned short* __restrict__ pre,
                                                   unsigned short* __restrict__ oh,
                                                   unsigned short* __restrict__ ol) {
    int node = blockIdx.x * 4 + (threadIdx.x >> 6);
    if (node >= N_NODES) return;
    int lane = threadIdx.x & 63;
    int c = lane * 8;                   // 8 consecutive columns per lane

    float di = dinv[node];
    float w0 = di * di;
    float s[8], t[8];
    {
        uint4 sv = *reinterpret_cast<const uint4*>(pre + (size_t)node * DIM + c);
        float fa[8]; cvt8(sv, fa);
        #pragma unroll
        for (int i = 0; i < 8; ++i) { s[i] = w0 * fa[i]; t[i] = 0.f; }
    }

    int beg = rowptr[node], end = rowptr[node + 1];
    int deg = end - beg;
    for (int j0 = 0; j0 < deg; j0 += 64) {
        int j = j0 + lane;
        int cj = 0; float wj = 0.f;
        if (j < deg) { cj = col[beg + j]; wj = wnorm[beg + j]; }
        int lim = deg - j0; if (lim > 64) lim = 64;
        // branchless chunks of 8: lanes beyond lim carry w=0
        for (int jj = 0; jj < lim; jj += 8) {
            int sidx[8]; float sw[8];
            #pragma unroll
            for (int q = 0; q < 8; ++q) {
                sidx[q] = __shfl(cj, jj + q);
                sw[q]   = __shfl(wj, jj + q);
            }
            uint4 v[8];
            #pragma unroll
            for (int q = 0; q < 8; ++q)
                v[q] = *reinterpret_cast<const uint4*>(pre + (size_t)sidx[q] * DIM + c);
            #pragma unroll
            for (int q = 0; q < 8; ++q) {
                float f[8]; cvt8(v[q], f);
                if ((q & 1) == 0) {
                    #pragma unroll
                    for (int i = 0; i < 8; ++i) s[i] = fmaf(sw[q], f[i], s[i]);
                } else {
                    #pragma unroll
                    for (int i = 0; i < 8; ++i) t[i] = fmaf(sw[q], f[i], t[i]);
                }
            }
        }
    }
    #pragma unroll
    for (int i = 0; i < 8; ++i) s[i] += t[i];

    size_t base = (size_t)node * DIM + c;
    if (OMODE == 1) {
        ush8v h, l;
        #pragma unroll
        for (int i = 0; i < 8; ++i) {
            unsigned short hh, ll;
            split1(s[i], hh, ll);
            h[i] = hh; l[i] = ll;
        }
        *reinterpret_cast<ush8v*>(oh + base) = h;
        *reinterpret_cast<ush8v*>(ol + base) = l;
    } else {
        ush8v h;
        #pragma unroll
        for (int i = 0; i < 8; ++i) h[i] = f2bf_rne(s[i]);
        *reinterpret_cast<ush8v*>(oh + base) = h;
    }
}

// ---------------- pool from bf16 A2 -> SPh/SPl directly ----------------
// SPh[0:1000] = A2b rsu rows (bf16 copy), SPl[0:1000] = 0 (exact: split(bf16)=(v,0)).
// SPh/SPl[1000+s] = split(seg-mean of A2b veh rows).
__global__ __launch_bounds__(64) void k_pool_sp(const unsigned short* __restrict__ A2b,
                                                const int* __restrict__ seg,
                                                unsigned short* __restrict__ SPh,
                                                unsigned short* __restrict__ SPl,
                                                float* __restrict__ bscale) {
    int s = blockIdx.x;            // 0..999
    int c = threadIdx.x * 8;       // 0..504
    // rsu row copy
    {
        uint4 v = *reinterpret_cast<const uint4*>(A2b + (size_t)s * DIM + c);
        *reinterpret_cast<uint4*>(SPh + (size_t)s * DIM + c) = v;
        ush8v z = {0, 0, 0, 0, 0, 0, 0, 0};
        *reinterpret_cast<ush8v*>(SPl + (size_t)s * DIM + c) = z;
    }
    // pooled mean
    int beg = seg[s], end = seg[s + 1];
    float acc[8] = {0.f, 0.f, 0.f, 0.f, 0.f, 0.f, 0.f, 0.f};
    for (int v = beg; v < end; ++v) {
        uint4 t = *reinterpret_cast<const uint4*>(A2b + (size_t)(NRSU + v) * DIM + c);
        float f[8]; cvt8(t, f);
        #pragma unroll
        for (int i = 0; i < 8; ++i) acc[i] += f[i];
    }
    float inv = 1.0f / fmaxf((float)(end - beg), 1.0f);
    ush8v h, l;
    #pragma unroll
    for (int i = 0; i < 8; ++i) {
        unsigned short hh, ll;
        split1(acc[i] * inv, hh, ll);
        h[i] = hh; l[i] = ll;
    }
    size_t base = (size_t)(NRSU + s) * DIM + c;
    *reinterpret_cast<ush8v*>(SPh + base) = h;
    *reinterpret_cast<ush8v*>(SPl + base) = l;
    if (threadIdx.x == 0) {
        bscale[s] = 1.0f;
        bscale[NRSU + s] = (end > beg) ? 1.0f : 0.0f;   // empty segment: ref gives exact 0
    }
}

extern "C" void kernel_launch(void* const* d_in, const int* in_sizes, int n_in,
                              void* d_out, int out_size, void* d_ws, size_t ws_size,
                              hipStream_t stream) {
    const float* x     = (const float*)d_in[0];
    const int*   ei    = (const int*)d_in[1];
    const int*   batch = (const int*)d_in[2];
    const float* W1    = (const float*)d_in[3];
    const float* b1    = (const float*)d_in[4];
    const float* W2    = (const float*)d_in[5];
    const float* b2    = (const float*)d_in[6];
    float* out = (float*)d_out;

    char* ws = (char*)d_ws;
    const size_t HALF = (size_t)N_NODES * DIM * 2;        // one bf16 plane (51.2 MB)
    // R0: Ax hi/lo bf16 planes; Axh reused as A2b (bf16) after GEMM1 consumes it
    unsigned short* Axh = (unsigned short*)(ws);
    unsigned short* Axl = (unsigned short*)(ws + HALF);
    unsigned short* A2b = (unsigned short*)(ws);
    // R1: h1 bf16 plane | x bf16 plane
    unsigned short* h1b = (unsigned short*)(ws + 2 * HALF);
    unsigned short* xb  = (unsigned short*)(ws + 3 * HALF);
    // Small region
    char* p = ws + 4 * HALF;
    float* dinv    = (float*)p;                p += (size_t)N_NODES * 4;
    int*   cnt     = (int*)p;                  p += (size_t)N_NODES * 4;   // reused as fill
    int*   rowptr  = (int*)p;                  p += (size_t)(N_NODES + 4) * 4;
    int*   col     = (int*)p;                  p += (size_t)E_EDGES * 4;
    float* wnorm   = (float*)p;                p += (size_t)E_EDGES * 4;
    int*   bsum    = (int*)p;                  p += 1024;
    int*   seg     = (int*)p;                  p += (size_t)(NRSU + 8) * 4;
    unsigned short* SPh = (unsigned short*)p;  p += (size_t)2 * NRSU * DIM * 2;
    unsigned short* SPl = (unsigned short*)p;  p += (size_t)2 * NRSU * DIM * 2;
    float* bscale  = (float*)p;                p += (size_t)2 * NRSU * 4;
    unsigned short* W1h = (unsigned short*)p;  p += (size_t)DIM * DIM * 2;
    unsigned short* W1l = (unsigned short*)p;  p += (size_t)DIM * DIM * 2;
    unsigned short* W2h = (unsigned short*)p;  p += (size_t)DIM * DIM * 2;
    unsigned short* W2l = (unsigned short*)p;  p += (size_t)DIM * DIM * 2;

    dim3 blk(256);
    const int gN = (N_NODES + 255) / 256;
    const int gE = (E_EDGES + 255) / 256;
    const int gV = (NVEH + 255) / 256;

    // ---- CSR build + norm + weight prep + x pre-round ----
    k_zero_int <<<gN, blk, 0, stream>>>(cnt, N_NODES);
    k_count    <<<gE, blk, 0, stream>>>(ei + E_EDGES, cnt);
    k_scan1    <<<gN, blk, 0, stream>>>(cnt, rowptr, bsum);
    k_scan2    <<<1,  blk, 0, stream>>>(bsum);
    k_scan3    <<<gN, blk, 0, stream>>>(rowptr, bsum, cnt, dinv);
    k_fill     <<<gE, blk, 0, stream>>>(ei, rowptr, cnt, col, dinv, wnorm);
    k_segbounds<<<gV, blk, 0, stream>>>(batch, seg);
    k_wsplit   <<<dim3(DIM, 2), blk, 0, stream>>>(W1, W2, W1h, W1l, W2h, W2l);
    k_tobf16   <<<(int)((size_t)N_NODES * DIM / 8 / 256), blk, 0, stream>>>(x, xb);

    // ---- layer 1: Ax = S*xb (split epilogue); h1b = bf16(relu(Ax@W1 + b1)) ----
    k_gather_bf<1><<<(N_NODES + 3) / 4, blk, 0, stream>>>(rowptr, col, wnorm, dinv, xb, Axh, Axl);
    const int NWG1 = ((N_NODES + 127) / 128) * 4;   // 1564
    k_gemm_mfma<2><<<NWG1, blk, 0, stream>>>(Axh, Axl, W1h, W1l, nullptr, h1b, N_NODES, b1, nullptr);

    // ---- layer 2: A2b = bf16(S*h1b); pool -> SPh/SPl; GEMM2 -> out ----
    k_gather_bf<2><<<(N_NODES + 3) / 4, blk, 0, stream>>>(rowptr, col, wnorm, dinv, h1b, A2b, nullptr);
    k_pool_sp<<<NRSU, dim3(64), 0, stream>>>(A2b, seg, SPh, SPl, bscale);
    const int NWG2 = ((2 * NRSU + 127) / 128) * 4;  // 64
    k_gemm_mfma<1><<<NWG2, blk, 0, stream>>>(SPh, SPl, W2h, W2l, out, nullptr, 2 * NRSU, b2, bscale);
}

// Round 13
// 354.805 us; speedup vs baseline: 1.9775x; 1.1216x over previous
//
#include <hip/hip_runtime.h>

#define N_NODES 50000
#define E_EDGES 400000
#define DIM     512
#define NRSU    1000
#define NVEH    (N_NODES - NRSU)
#define NB_SCAN 196           // ceil(50000/256)

typedef __attribute__((ext_vector_type(8))) __bf16 bf16x8;
typedef __attribute__((ext_vector_type(4))) float  f32x4;
typedef __attribute__((ext_vector_type(8))) unsigned short ush8v;

// ---------- bf16 helpers (RNE) ----------
__device__ __forceinline__ unsigned short f2bf_rne(float x) {
    unsigned u = __float_as_uint(x);
    unsigned r = u + 0x7fff + ((u >> 16) & 1);
    return (unsigned short)(r >> 16);
}
__device__ __forceinline__ float bf2f(unsigned short b) {
    return __uint_as_float((unsigned)b << 16);
}
__device__ __forceinline__ void split1(float v, unsigned short& h, unsigned short& l) {
    h = f2bf_rne(v);
    l = f2bf_rne(v - bf2f(h));
}
// unpack 8 packed bf16 (uint4) -> 8 floats
__device__ __forceinline__ void cvt8(uint4 v, float* f) {
    f[0] = __uint_as_float(v.x << 16); f[1] = __uint_as_float(v.x & 0xffff0000u);
    f[2] = __uint_as_float(v.y << 16); f[3] = __uint_as_float(v.y & 0xffff0000u);
    f[4] = __uint_as_float(v.z << 16); f[5] = __uint_as_float(v.z & 0xffff0000u);
    f[6] = __uint_as_float(v.w << 16); f[7] = __uint_as_float(v.w & 0xffff0000u);
}

// ---------- async global->LDS (16B per lane) ----------
typedef __attribute__((address_space(1))) const unsigned char ga_u8;
typedef __attribute__((address_space(3))) unsigned char la_u8;
__device__ __forceinline__ void gload16(const void* g, void* l) {
    __builtin_amdgcn_global_load_lds((ga_u8*)g, (la_u8*)l, 16, 0, 0);
}

// ---------------- zero int array ----------------
__global__ void k_zero_int(int* __restrict__ p, int n) {
    int i = blockIdx.x * 256 + threadIdx.x;
    if (i < n) p[i] = 0;
}

// ---------------- fp32 -> bf16 round (x pre-round) ----------------
__global__ void k_tobf16(const float* __restrict__ in, unsigned short* __restrict__ out) {
    size_t i = ((size_t)blockIdx.x * 256 + threadIdx.x) * 8;
    float4 a = *reinterpret_cast<const float4*>(in + i);
    float4 b = *reinterpret_cast<const float4*>(in + i + 4);
    ush8v o;
    o[0] = f2bf_rne(a.x); o[1] = f2bf_rne(a.y); o[2] = f2bf_rne(a.z); o[3] = f2bf_rne(a.w);
    o[4] = f2bf_rne(b.x); o[5] = f2bf_rne(b.y); o[6] = f2bf_rne(b.z); o[7] = f2bf_rne(b.w);
    *reinterpret_cast<ush8v*>(out + i) = o;
}

// ---------------- in-degree count ----------------
__global__ void k_count(const int* __restrict__ dst, int* __restrict__ cnt) {
    int e = blockIdx.x * 256 + threadIdx.x;
    if (e < E_EDGES) atomicAdd(&cnt[dst[e]], 1);
}

// ---------------- block-wise exclusive scan ----------------
__global__ __launch_bounds__(256) void k_scan1(const int* __restrict__ cnt,
                                               int* __restrict__ rowptr,
                                               int* __restrict__ bsum) {
    __shared__ int sh[256];
    int tid = threadIdx.x;
    int i = blockIdx.x * 256 + tid;
    int v = (i < N_NODES) ? cnt[i] : 0;
    sh[tid] = v;
    __syncthreads();
    #pragma unroll
    for (int off = 1; off < 256; off <<= 1) {
        int t = (tid >= off) ? sh[tid - off] : 0;
        __syncthreads();
        sh[tid] += t;
        __syncthreads();
    }
    if (i < N_NODES) rowptr[i] = sh[tid] - v;
    if (tid == 255) bsum[blockIdx.x] = sh[255];
}

__global__ __launch_bounds__(256) void k_scan2(int* __restrict__ bsum) {
    __shared__ int sh[256];
    int tid = threadIdx.x;
    int v = (tid < NB_SCAN) ? bsum[tid] : 0;
    sh[tid] = v;
    __syncthreads();
    #pragma unroll
    for (int off = 1; off < 256; off <<= 1) {
        int t = (tid >= off) ? sh[tid - off] : 0;
        __syncthreads();
        sh[tid] += t;
        __syncthreads();
    }
    if (tid < NB_SCAN) bsum[tid] = sh[tid] - v;
}

// scan finalize + dinv + zero fill counters (merged)
__global__ void k_scan3(int* __restrict__ rowptr, const int* __restrict__ bsum,
                        int* __restrict__ cntfill, float* __restrict__ dinv) {
    int i = blockIdx.x * 256 + threadIdx.x;
    if (i < N_NODES) {
        rowptr[i] += bsum[blockIdx.x];
        int c = cntfill[i];
        dinv[i] = rsqrtf((float)c + 1.0f);   // self-loop
        cntfill[i] = 0;                      // becomes fill counter
    }
    if (i == 0) rowptr[N_NODES] = E_EDGES;
}

// ---------------- CSR fill (+ precomputed edge weights) ----------------
__global__ void k_fill(const int* __restrict__ ei, const int* __restrict__ rowptr,
                       int* __restrict__ fill, int* __restrict__ col,
                       const float* __restrict__ dinv, float* __restrict__ wnorm) {
    int e = blockIdx.x * 256 + threadIdx.x;
    if (e >= E_EDGES) return;
    int s = ei[e];
    int d = ei[E_EDGES + e];
    int p = atomicAdd(&fill[d], 1);
    int idx = rowptr[d] + p;
    col[idx] = s;
    wnorm[idx] = dinv[s] * dinv[d];
}

// ---------------- segment boundaries (batch monotone over vehicles) ----
__global__ void k_segbounds(const int* __restrict__ batch, int* __restrict__ seg) {
    int v = blockIdx.x * 256 + threadIdx.x;
    if (v >= NVEH) return;
    int b = batch[NRSU + v];
    if (v == 0) {
        for (int s = 0; s <= b; ++s) seg[s] = 0;
    } else {
        int bp = batch[NRSU + v - 1];
        for (int s = bp + 1; s <= b; ++s) seg[s] = v;
    }
    if (v == NVEH - 1) {
        for (int s = b + 1; s <= NRSU; ++s) seg[s] = NVEH;
    }
}

// ---------------- both W [K][N] -> W^T split bf16 hi/lo [N][K] ----------------
__global__ void k_wsplit(const float* __restrict__ W1, const float* __restrict__ W2,
                         unsigned short* __restrict__ W1h, unsigned short* __restrict__ W1l,
                         unsigned short* __restrict__ W2h, unsigned short* __restrict__ W2l) {
    const float* W = blockIdx.y ? W2 : W1;
    unsigned short* Wh = blockIdx.y ? W2h : W1h;
    unsigned short* Wl = blockIdx.y ? W2l : W1l;
    int n = blockIdx.x;
    for (int k = threadIdx.x; k < DIM; k += 256) {
        float v = W[(size_t)k * DIM + n];
        unsigned short h, l;
        split1(v, h, l);
        Wh[(size_t)n * DIM + k] = h;
        Wl[(size_t)n * DIM + k] = l;
    }
}

// ---------------- 2-term split-bf16 MFMA GEMM (A single bf16, W hi/lo) ----------------
// Swizzle: 16B-slot s at row r holds k-chunk (s ^ ((r>>1)&3)) -> bank-granule
// (r*4+s) mod 8 hits each value twice per 16-lane group (2-way = free).
// MODE 1: M=2000 "[rsu; pooled]" rows -> out (fp32) concat layout, + b[col]*bscale[row]
// MODE 2: Cb[M x 512] (bf16) = relu(A@B + bias), 1-D grid with bijective XCD remap
template<int MODE>
__global__ __launch_bounds__(256) void k_gemm_mfma(const unsigned short* __restrict__ Ab,
                                                   const unsigned short* __restrict__ BhT,
                                                   const unsigned short* __restrict__ BlT,
                                                   float* __restrict__ C,
                                                   unsigned short* __restrict__ Cb, int M,
                                                   const float* __restrict__ bias,
                                                   const float* __restrict__ bscale) {
    const int BM = 128, BN = 128, BK = 32;
    __shared__ unsigned short sA [BM * BK];   // 8 KB each, 24 KB total
    __shared__ unsigned short sBh[BN * BK];
    __shared__ unsigned short sBl[BN * BK];

    int tid = threadIdx.x;
    int wv = tid >> 6;
    int ln = tid & 63;

    int wgid;
    if (MODE == 2) {
        // bijective XCD-chunk remap: nwg = 1564 = 8*195 + 4
        const int q = 195, r = 4;
        int id = blockIdx.x;
        int xcd = id & 7, idx = id >> 3;
        wgid = (xcd < r ? xcd * (q + 1) : r * (q + 1) + (xcd - r) * q) + idx;
    } else {
        wgid = blockIdx.x;
    }
    int col0 = (wgid & 3) * BN;        // col fastest: 4 col-tiles share A row-panel
    int row0 = (wgid >> 2) * BM;

    int wr = wv >> 1, wc = wv & 1;     // 2x2 waves, each 64x64
    int fr = ln & 15;
    int ks16 = ln >> 4;                // k-chunk 0..3

    f32x4 zero = {0.f, 0.f, 0.f, 0.f};
    f32x4 acc[4][4];
    #pragma unroll
    for (int m = 0; m < 4; ++m)
        #pragma unroll
        for (int n = 0; n < 4; ++n) acc[m][n] = zero;

    for (int k0 = 0; k0 < DIM; k0 += BK) {
        __syncthreads();
        #pragma unroll
        for (int p = 0; p < 2; ++p) {
            int idx = p * 256 + tid;           // (row, slot): row = idx>>2, slot = idx&3
            int r = idx >> 2;
            int slot = idx & 3;
            int c = ((slot ^ ((r >> 1) & 3)) << 3);   // pre-swizzled global k-chunk
            int arow = row0 + r; if (arow > M - 1) arow = M - 1;
            size_t aoff = (size_t)arow * DIM + k0 + c;
            size_t boff = (size_t)(col0 + r) * DIM + k0 + c;
            int lbyte = p * 4096 + wv * 1024;  // linear wave-uniform LDS dest
            gload16(Ab + aoff, (char*)sA + lbyte);
            gload16(BhT + boff, (char*)sBh + lbyte);
            gload16(BlT + boff, (char*)sBl + lbyte);
        }
        __syncthreads();

        bf16x8 a[4], bh[4], bl[4];
        #pragma unroll
        for (int m = 0; m < 4; ++m) {
            int r = wr * 64 + m * 16 + fr;
            int e = r * BK + ((ks16 ^ ((r >> 1) & 3)) << 3);
            a[m] = *reinterpret_cast<const bf16x8*>(&sA[e]);
        }
        #pragma unroll
        for (int n = 0; n < 4; ++n) {
            int r = wc * 64 + n * 16 + fr;
            int e = r * BK + ((ks16 ^ ((r >> 1) & 3)) << 3);
            bh[n] = *reinterpret_cast<const bf16x8*>(&sBh[e]);
            bl[n] = *reinterpret_cast<const bf16x8*>(&sBl[e]);
        }
        #pragma unroll
        for (int m = 0; m < 4; ++m)
            #pragma unroll
            for (int n = 0; n < 4; ++n) {
                acc[m][n] = __builtin_amdgcn_mfma_f32_16x16x32_bf16(a[m], bh[n], acc[m][n], 0, 0, 0);
                acc[m][n] = __builtin_amdgcn_mfma_f32_16x16x32_bf16(a[m], bl[n], acc[m][n], 0, 0, 0);
            }
    }

    int rbase = row0 + wr * 64 + (ln >> 4) * 4;
    int cbase = col0 + wc * 64 + (ln & 15);
    #pragma unroll
    for (int m = 0; m < 4; ++m)
        #pragma unroll
        for (int r4 = 0; r4 < 4; ++r4) {
            int row = rbase + m * 16 + r4;
            if (row < M) {
                if (MODE == 2) {
                    #pragma unroll
                    for (int n = 0; n < 4; ++n) {
                        int cc = cbase + n * 16;
                        Cb[(size_t)row * DIM + cc] =
                            f2bf_rne(fmaxf(acc[m][n][r4] + bias[cc], 0.f));
                    }
                } else {
                    float bs = bscale[row];
                    float* dst = (row < NRSU) ? (C + (size_t)row * 1024)
                                              : (C + (size_t)(row - NRSU) * 1024 + 512);
                    #pragma unroll
                    for (int n = 0; n < 4; ++n) {
                        int cc = cbase + n * 16;
                        dst[cc] = acc[m][n][r4] + bias[cc] * bs;
                    }
                }
            }
        }
}

// ---------------- CSR gather on bf16 rows -> single bf16 plane ----------------
__global__ __launch_bounds__(256) void k_gather_bf(const int* __restrict__ rowptr,
                                                   const int* __restrict__ col,
                                                   const float* __restrict__ wnorm,
                                                   const float* __restrict__ dinv,
                                                   const unsigned short* __restrict__ pre,
                                                   unsigned short* __restrict__ ob) {
    int node = blockIdx.x * 4 + (threadIdx.x >> 6);
    if (node >= N_NODES) return;
    int lane = threadIdx.x & 63;
    int c = lane * 8;                   // 8 consecutive columns per lane

    float di = dinv[node];
    float w0 = di * di;
    float s[8], t[8];
    {
        uint4 sv = *reinterpret_cast<const uint4*>(pre + (size_t)node * DIM + c);
        float fa[8]; cvt8(sv, fa);
        #pragma unroll
        for (int i = 0; i < 8; ++i) { s[i] = w0 * fa[i]; t[i] = 0.f; }
    }

    int beg = rowptr[node], end = rowptr[node + 1];
    int deg = end - beg;
    for (int j0 = 0; j0 < deg; j0 += 64) {
        int j = j0 + lane;
        int cj = 0; float wj = 0.f;
        if (j < deg) { cj = col[beg + j]; wj = wnorm[beg + j]; }
        int lim = deg - j0; if (lim > 64) lim = 64;
        // branchless chunks of 8: lanes beyond lim carry w=0
        for (int jj = 0; jj < lim; jj += 8) {
            int sidx[8]; float sw[8];
            #pragma unroll
            for (int q = 0; q < 8; ++q) {
                sidx[q] = __shfl(cj, jj + q);
                sw[q]   = __shfl(wj, jj + q);
            }
            uint4 v[8];
            #pragma unroll
            for (int q = 0; q < 8; ++q)
                v[q] = *reinterpret_cast<const uint4*>(pre + (size_t)sidx[q] * DIM + c);
            #pragma unroll
            for (int q = 0; q < 8; ++q) {
                float f[8]; cvt8(v[q], f);
                if ((q & 1) == 0) {
                    #pragma unroll
                    for (int i = 0; i < 8; ++i) s[i] = fmaf(sw[q], f[i], s[i]);
                } else {
                    #pragma unroll
                    for (int i = 0; i < 8; ++i) t[i] = fmaf(sw[q], f[i], t[i]);
                }
            }
        }
    }
    ush8v h;
    #pragma unroll
    for (int i = 0; i < 8; ++i) h[i] = f2bf_rne(s[i] + t[i]);
    *reinterpret_cast<ush8v*>(ob + (size_t)node * DIM + c) = h;
}

// ---------------- pool from bf16 A2 -> single SPb plane ----------------
// SPb[0:1000] = A2b rsu rows (copy); SPb[1000+s] = bf16(seg-mean of A2b veh rows).
__global__ __launch_bounds__(64) void k_pool_sp(const unsigned short* __restrict__ A2b,
                                                const int* __restrict__ seg,
                                                unsigned short* __restrict__ SPb,
                                                float* __restrict__ bscale) {
    int s = blockIdx.x;            // 0..999
    int c = threadIdx.x * 8;       // 0..504
    {
        uint4 v = *reinterpret_cast<const uint4*>(A2b + (size_t)s * DIM + c);
        *reinterpret_cast<uint4*>(SPb + (size_t)s * DIM + c) = v;
    }
    int beg = seg[s], end = seg[s + 1];
    float acc[8] = {0.f, 0.f, 0.f, 0.f, 0.f, 0.f, 0.f, 0.f};
    for (int v = beg; v < end; ++v) {
        uint4 t = *reinterpret_cast<const uint4*>(A2b + (size_t)(NRSU + v) * DIM + c);
        float f[8]; cvt8(t, f);
        #pragma unroll
        for (int i = 0; i < 8; ++i) acc[i] += f[i];
    }
    float inv = 1.0f / fmaxf((float)(end - beg), 1.0f);
    ush8v h;
    #pragma unroll
    for (int i = 0; i < 8; ++i) h[i] = f2bf_rne(acc[i] * inv);
    *reinterpret_cast<ush8v*>(SPb + (size_t)(NRSU + s) * DIM + c) = h;
    if (threadIdx.x == 0) {
        bscale[s] = 1.0f;
        bscale[NRSU + s] = (end > beg) ? 1.0f : 0.0f;   // empty segment: ref gives exact 0
    }
}

extern "C" void kernel_launch(void* const* d_in, const int* in_sizes, int n_in,
                              void* d_out, int out_size, void* d_ws, size_t ws_size,
                              hipStream_t stream) {
    const float* x     = (const float*)d_in[0];
    const int*   ei    = (const int*)d_in[1];
    const int*   batch = (const int*)d_in[2];
    const float* W1    = (const float*)d_in[3];
    const float* b1    = (const float*)d_in[4];
    const float* W2    = (const float*)d_in[5];
    const float* b2    = (const float*)d_in[6];
    float* out = (float*)d_out;

    char* ws = (char*)d_ws;
    const size_t HALF = (size_t)N_NODES * DIM * 2;        // one bf16 plane (51.2 MB)
    // R0: Axb plane; reused as A2b after GEMM1 consumes it
    unsigned short* Axb = (unsigned short*)(ws);
    unsigned short* A2b = (unsigned short*)(ws);
    // R1: h1 bf16 plane | x bf16 plane
    unsigned short* h1b = (unsigned short*)(ws + 2 * HALF);
    unsigned short* xb  = (unsigned short*)(ws + 3 * HALF);
    // Small region
    char* p = ws + 4 * HALF;
    float* dinv    = (float*)p;                p += (size_t)N_NODES * 4;
    int*   cnt     = (int*)p;                  p += (size_t)N_NODES * 4;   // reused as fill
    int*   rowptr  = (int*)p;                  p += (size_t)(N_NODES + 4) * 4;
    int*   col     = (int*)p;                  p += (size_t)E_EDGES * 4;
    float* wnorm   = (float*)p;                p += (size_t)E_EDGES * 4;
    int*   bsum    = (int*)p;                  p += 1024;
    int*   seg     = (int*)p;                  p += (size_t)(NRSU + 8) * 4;
    unsigned short* SPb = (unsigned short*)p;  p += (size_t)2 * NRSU * DIM * 2;
    float* bscale  = (float*)p;                p += (size_t)2 * NRSU * 4;
    unsigned short* W1h = (unsigned short*)p;  p += (size_t)DIM * DIM * 2;
    unsigned short* W1l = (unsigned short*)p;  p += (size_t)DIM * DIM * 2;
    unsigned short* W2h = (unsigned short*)p;  p += (size_t)DIM * DIM * 2;
    unsigned short* W2l = (unsigned short*)p;  p += (size_t)DIM * DIM * 2;

    dim3 blk(256);
    const int gN = (N_NODES + 255) / 256;
    const int gE = (E_EDGES + 255) / 256;
    const int gV = (NVEH + 255) / 256;

    // ---- CSR build + norm + weight prep + x pre-round ----
    k_zero_int <<<gN, blk, 0, stream>>>(cnt, N_NODES);
    k_count    <<<gE, blk, 0, stream>>>(ei + E_EDGES, cnt);
    k_scan1    <<<gN, blk, 0, stream>>>(cnt, rowptr, bsum);
    k_scan2    <<<1,  blk, 0, stream>>>(bsum);
    k_scan3    <<<gN, blk, 0, stream>>>(rowptr, bsum, cnt, dinv);
    k_fill     <<<gE, blk, 0, stream>>>(ei, rowptr, cnt, col, dinv, wnorm);
    k_segbounds<<<gV, blk, 0, stream>>>(batch, seg);
    k_wsplit   <<<dim3(DIM, 2), blk, 0, stream>>>(W1, W2, W1h, W1l, W2h, W2l);
    k_tobf16   <<<(int)((size_t)N_NODES * DIM / 8 / 256), blk, 0, stream>>>(x, xb);

    // ---- layer 1: Axb = bf16(S*xb); h1b = bf16(relu(Axb@W1 + b1)) ----
    k_gather_bf<<<(N_NODES + 3) / 4, blk, 0, stream>>>(rowptr, col, wnorm, dinv, xb, Axb);
    const int NWG1 = ((N_NODES + 127) / 128) * 4;   // 1564
    k_gemm_mfma<2><<<NWG1, blk, 0, stream>>>(Axb, W1h, W1l, nullptr, h1b, N_NODES, b1, nullptr);

    // ---- layer 2: A2b = bf16(S*h1b); pool -> SPb; GEMM2 -> out ----
    k_gather_bf<<<(N_NODES + 3) / 4, blk, 0, stream>>>(rowptr, col, wnorm, dinv, h1b, A2b);
    k_pool_sp<<<NRSU, dim3(64), 0, stream>>>(A2b, seg, SPb, bscale);
    const int NWG2 = ((2 * NRSU + 127) / 128) * 4;  // 64
    k_gemm_mfma<1><<<NWG2, blk, 0, stream>>>(SPb, W2h, W2l, out, nullptr, 2 * NRSU, b2, bscale);
}